// Round 1
// baseline (624.248 us; speedup 1.0000x reference)
//
#include <hip/hip_runtime.h>
#include <math.h>

#define NN 65536        // nodes
#define NE 524288       // edges (without self loops)
#define D 128
#define ED 32
#define NEG_SLOPE 0.2f

__device__ __forceinline__ float leaky(float x) { return x > 0.f ? x : NEG_SLOPE * x; }
__device__ __forceinline__ float gelu_exact(float x) {
    return 0.5f * x * (1.f + erff(x * 0.70710678118654752440f));
}

// ---------------- CSR build ----------------

__global__ void k_hist(const int* __restrict__ dst, int* __restrict__ deg) {
    int e = blockIdx.x * 256 + threadIdx.x;
    atomicAdd(&deg[dst[e]], 1);
}

__global__ void k_scan1(const int* __restrict__ deg, int* __restrict__ rp, int* __restrict__ bsum) {
    __shared__ int s[256];
    int t = threadIdx.x;
    int i = blockIdx.x * 256 + t;
    int v = deg[i];
    s[t] = v;
    __syncthreads();
    #pragma unroll
    for (int off = 1; off < 256; off <<= 1) {
        int x = (t >= off) ? s[t - off] : 0;
        __syncthreads();
        s[t] += x;
        __syncthreads();
    }
    rp[i] = s[t] - v;                       // block-local exclusive
    if (t == 255) bsum[blockIdx.x] = s[t];  // block total
}

__global__ void k_scan2(const int* __restrict__ bsum, int* __restrict__ bscan, int* __restrict__ rp) {
    __shared__ int s[256];
    int t = threadIdx.x;
    int v = bsum[t];
    s[t] = v;
    __syncthreads();
    #pragma unroll
    for (int off = 1; off < 256; off <<= 1) {
        int x = (t >= off) ? s[t - off] : 0;
        __syncthreads();
        s[t] += x;
        __syncthreads();
    }
    bscan[t] = s[t] - v;
    if (t == 255) rp[NN] = s[t];  // == NE
}

__global__ void k_scan3(int* __restrict__ rp, const int* __restrict__ bscan, int* __restrict__ cursor) {
    int i = blockIdx.x * 256 + threadIdx.x;
    int v = rp[i] + bscan[blockIdx.x];
    rp[i] = v;
    cursor[i] = v;
}

__global__ void k_scatter(const int* __restrict__ srcArr, const int* __restrict__ dstArr,
                          int* __restrict__ cursor, int* __restrict__ csr_src, int* __restrict__ csr_eid) {
    int e = blockIdx.x * 256 + threadIdx.x;
    int d = dstArr[e];
    int p = atomicAdd(&cursor[d], 1);
    csr_src[p] = srcArr[e];
    csr_eid[p] = e;
}

// ---------------- edge-attr precompute ----------------

// wvec[l][k] = dot(W_edge[l][k][:], att_edge[l][:])   (3 x 32)
__global__ void k_wvec(const float* __restrict__ We, const float* __restrict__ ae, float* __restrict__ wvec) {
    int t = threadIdx.x;
    if (t < 3 * ED) {
        int l = t / ED, k = t % ED;
        const float* w = We + (long)(l * ED + k) * D;
        const float* a = ae + (long)l * D;
        float s = 0.f;
        #pragma unroll
        for (int i = 0; i < D; ++i) s += w[i] * a[i];
        wvec[t] = s;
    }
}

// ale[l*NE + e] = dot(ea[e][:], wvec[l][:])
__global__ void k_ale(const float* __restrict__ ea, const float* __restrict__ wvec, float* __restrict__ ale) {
    int e = blockIdx.x * 256 + threadIdx.x;
    const float4* row = (const float4*)(ea + (long)e * ED);
    const float4* w0 = (const float4*)(wvec);
    const float4* w1 = (const float4*)(wvec + ED);
    const float4* w2 = (const float4*)(wvec + 2 * ED);
    float s0 = 0.f, s1 = 0.f, s2 = 0.f;
    #pragma unroll
    for (int i = 0; i < ED / 4; ++i) {
        float4 v = row[i];
        float4 a = w0[i], b = w1[i], c = w2[i];
        s0 += v.x * a.x + v.y * a.y + v.z * a.z + v.w * a.w;
        s1 += v.x * b.x + v.y * b.y + v.z * b.z + v.w * b.w;
        s2 += v.x * c.x + v.y * c.y + v.z * c.z + v.w * c.w;
    }
    ale[e] = s0;
    ale[NE + e] = s1;
    ale[2 * NE + e] = s2;
}

// ale_self[l*NN + n] = dot(mean incoming ea (0 if none), wvec[l])
// one 32-lane half-wave per node
__global__ void k_ale_self(const float* __restrict__ ea, const int* __restrict__ rp,
                           const int* __restrict__ csr_eid, const float* __restrict__ wvec,
                           float* __restrict__ ale_self) {
    int t = threadIdx.x;
    int n = blockIdx.x * 8 + (t >> 5);
    int lane = t & 31;
    int s = rp[n], e = rp[n + 1];
    float sum = 0.f;
    for (int j = s; j < e; ++j) {
        int eid = csr_eid[j];
        sum += ea[(long)eid * ED + lane];
    }
    int degn = e - s;
    float fill = (degn > 0) ? sum / (float)degn : 0.f;
    #pragma unroll
    for (int l = 0; l < 3; ++l) {
        float p = fill * wvec[l * ED + lane];
        #pragma unroll
        for (int off = 16; off > 0; off >>= 1) p += __shfl_xor(p, off);
        if (lane == 0) ale_self[l * NN + n] = p;
    }
}

// ---------------- per-layer kernels ----------------

// C[M x 128] = A[M x 128] @ W[128 x 128], fp32; 64 rows per block, 256 threads
__global__ __launch_bounds__(256) void k_gemm(const float* __restrict__ A, const float* __restrict__ Wm,
                                              float* __restrict__ C) {
    __shared__ float xs[64 * 128];   // 32 KB
    __shared__ float wsh[32 * 128];  // 16 KB
    int t = threadIdx.x;
    int tx = t & 31;   // 4 cols: 4*tx .. 4*tx+3
    int ty = t >> 5;   // 8 rows: 8*ty .. 8*ty+7
    const float4* A4 = (const float4*)(A + (long)blockIdx.x * 64 * 128);
    float4* xs4 = (float4*)xs;
    #pragma unroll
    for (int i = 0; i < 8; ++i) xs4[t + 256 * i] = A4[t + 256 * i];

    float acc[8][4] = {};
    for (int kc = 0; kc < 128; kc += 32) {
        __syncthreads();
        const float4* W4 = (const float4*)(Wm + kc * 128);
        float4* ws4 = (float4*)wsh;
        #pragma unroll
        for (int i = 0; i < 4; ++i) ws4[t + 256 * i] = W4[t + 256 * i];
        __syncthreads();
        #pragma unroll
        for (int k4 = 0; k4 < 8; ++k4) {
            float4 b0 = *(const float4*)&wsh[(k4 * 4 + 0) * 128 + tx * 4];
            float4 b1 = *(const float4*)&wsh[(k4 * 4 + 1) * 128 + tx * 4];
            float4 b2 = *(const float4*)&wsh[(k4 * 4 + 2) * 128 + tx * 4];
            float4 b3 = *(const float4*)&wsh[(k4 * 4 + 3) * 128 + tx * 4];
            #pragma unroll
            for (int i = 0; i < 8; ++i) {
                float4 a = *(const float4*)&xs[(ty * 8 + i) * 128 + kc + k4 * 4];
                acc[i][0] += a.x * b0.x + a.y * b1.x + a.z * b2.x + a.w * b3.x;
                acc[i][1] += a.x * b0.y + a.y * b1.y + a.z * b2.y + a.w * b3.y;
                acc[i][2] += a.x * b0.z + a.y * b1.z + a.z * b2.z + a.w * b3.z;
                acc[i][3] += a.x * b0.w + a.y * b1.w + a.z * b2.w + a.w * b3.w;
            }
        }
    }
    long rowBase = (long)blockIdx.x * 64;
    #pragma unroll
    for (int i = 0; i < 8; ++i) {
        float4 v = make_float4(acc[i][0], acc[i][1], acc[i][2], acc[i][3]);
        *(float4*)&C[(rowBase + ty * 8 + i) * 128 + tx * 4] = v;
    }
}

// als[n] = dot(h[n], a_s), ald[n] = dot(h[n], a_d); one wave per node
__global__ __launch_bounds__(256) void k_att(const float* __restrict__ h, const float* __restrict__ a_s,
                                             const float* __restrict__ a_d, float* __restrict__ als,
                                             float* __restrict__ ald) {
    int wave = threadIdx.x >> 6, lane = threadIdx.x & 63;
    int n = blockIdx.x * 4 + wave;
    float2 hv = ((const float2*)(h + (long)n * D))[lane];
    float2 as2 = ((const float2*)a_s)[lane];
    float2 ad2 = ((const float2*)a_d)[lane];
    float ps = hv.x * as2.x + hv.y * as2.y;
    float pd = hv.x * ad2.x + hv.y * ad2.y;
    #pragma unroll
    for (int off = 32; off > 0; off >>= 1) {
        ps += __shfl_xor(ps, off);
        pd += __shfl_xor(pd, off);
    }
    if (lane == 0) { als[n] = ps; ald[n] = pd; }
}

// online-softmax aggregation, one wave per dst node; lane covers cols {2*lane, 2*lane+1}
__global__ __launch_bounds__(256) void k_aggr(const float* __restrict__ h, const float* __restrict__ als,
                                              const float* __restrict__ ald, const float* __restrict__ ale,
                                              const float* __restrict__ ale_self, const int* __restrict__ rp,
                                              const int* __restrict__ csr_src, const int* __restrict__ csr_eid,
                                              const float* __restrict__ bias, float* __restrict__ out) {
    int wave = threadIdx.x >> 6, lane = threadIdx.x & 63;
    int d = blockIdx.x * 4 + wave;
    int s0 = rp[d], s1 = rp[d + 1];
    float aldd = ald[d];
    // self loop (always present): init online-softmax state with it
    float m = leaky(als[d] + aldd + ale_self[d]);
    float den = 1.f;
    float2 hv = ((const float2*)(h + (long)d * D))[lane];
    float ax = hv.x, ay = hv.y;
    for (int base = s0; base < s1; base += 64) {
        int cnt = min(s1 - base, 64);
        int srcn = 0;
        float al = 0.f;
        if (lane < cnt) {
            int j = base + lane;
            srcn = csr_src[j];
            al = leaky(als[srcn] + aldd + ale[csr_eid[j]]);
        }
        for (int t = 0; t < cnt; ++t) {
            float alt = __shfl(al, t);
            int st = __shfl(srcn, t);
            float mn = fmaxf(m, alt);
            float sc = __expf(m - mn);
            float p = __expf(alt - mn);
            float2 hs = ((const float2*)(h + (long)st * D))[lane];
            den = den * sc + p;
            ax = ax * sc + p * hs.x;
            ay = ay * sc + p * hs.y;
            m = mn;
        }
    }
    float inv = 1.f / den;
    float2 b2 = ((const float2*)bias)[lane];
    float ox = gelu_exact(ax * inv + b2.x);
    float oy = gelu_exact(ay * inv + b2.y);
    ((float2*)(out + (long)d * D))[lane] = make_float2(ox, oy);
}

// ---------------- launch ----------------

extern "C" void kernel_launch(void* const* d_in, const int* in_sizes, int n_in,
                              void* d_out, int out_size, void* d_ws, size_t ws_size,
                              hipStream_t stream) {
    (void)in_sizes; (void)n_in; (void)out_size; (void)ws_size;
    const float* x        = (const float*)d_in[0];
    const int*   eidx     = (const int*)d_in[1];   // [2, NE]: row0=src, row1=dst
    const float* ea       = (const float*)d_in[2];
    const float* Ws       = (const float*)d_in[3];
    const float* att_src  = (const float*)d_in[4];
    const float* att_dst  = (const float*)d_in[5];
    const float* W_edge   = (const float*)d_in[6];
    const float* att_edge = (const float*)d_in[7];
    const float* bias     = (const float*)d_in[8];
    float* out = (float*)d_out;

    char* ws = (char*)d_ws;
    size_t off = 0;
    auto alloc = [&](size_t bytes) {
        void* p = ws + off;
        off += (bytes + 255) & ~(size_t)255;
        return p;
    };
    float* B0       = (float*)alloc((size_t)NN * D * 4);   // h after GEMM
    float* als      = (float*)alloc((size_t)NN * 4);
    float* ald      = (float*)alloc((size_t)NN * 4);
    float* ale      = (float*)alloc((size_t)3 * NE * 4);
    float* ale_self = (float*)alloc((size_t)3 * NN * 4);
    float* wvec     = (float*)alloc(3 * ED * 4);
    int*   deg      = (int*)alloc((size_t)NN * 4);
    int*   rp       = (int*)alloc((size_t)(NN + 4) * 4);
    int*   cursor   = (int*)alloc((size_t)NN * 4);
    int*   bsum     = (int*)alloc(256 * 4);
    int*   bscan    = (int*)alloc(256 * 4);
    int*   csr_src  = (int*)alloc((size_t)NE * 4);
    int*   csr_eid  = (int*)alloc((size_t)NE * 4);

    const int* e_src = eidx;
    const int* e_dst = eidx + NE;

    // CSR build
    hipMemsetAsync(deg, 0, (size_t)NN * 4, stream);
    k_hist<<<NE / 256, 256, 0, stream>>>(e_dst, deg);
    k_scan1<<<NN / 256, 256, 0, stream>>>(deg, rp, bsum);
    k_scan2<<<1, 256, 0, stream>>>(bsum, bscan, rp);
    k_scan3<<<NN / 256, 256, 0, stream>>>(rp, bscan, cursor);
    k_scatter<<<NE / 256, 256, 0, stream>>>(e_src, e_dst, cursor, csr_src, csr_eid);

    // edge-attr precompute (shared across layers)
    k_wvec<<<1, 128, 0, stream>>>(W_edge, att_edge, wvec);
    k_ale<<<NE / 256, 256, 0, stream>>>(ea, wvec, ale);
    k_ale_self<<<NN / 8, 256, 0, stream>>>(ea, rp, csr_eid, wvec, ale_self);

    // layers; d_out doubles as the h ping-pong buffer
    const float* hin = x;
    for (int l = 0; l < 3; ++l) {
        k_gemm<<<NN / 64, 256, 0, stream>>>(hin, Ws + (size_t)l * D * D, B0);
        k_att<<<NN / 4, 256, 0, stream>>>(B0, att_src + (size_t)l * D, att_dst + (size_t)l * D, als, ald);
        k_aggr<<<NN / 4, 256, 0, stream>>>(B0, als, ald, ale + (size_t)l * NE, ale_self + (size_t)l * NN,
                                           rp, csr_src, csr_eid, bias + (size_t)l * D, out);
        hin = out;
    }
}

// Round 2
// 582.707 us; speedup vs baseline: 1.0713x; 1.0713x over previous
//
#include <hip/hip_runtime.h>
#include <math.h>

#define NN 65536        // nodes
#define NE 524288       // edges (without self loops)
#define D 128
#define ED 32
#define NEG_SLOPE 0.2f

typedef short bf16x8 __attribute__((ext_vector_type(8)));
typedef float f32x4 __attribute__((ext_vector_type(4)));

__device__ __forceinline__ float leaky(float x) { return x > 0.f ? x : NEG_SLOPE * x; }
__device__ __forceinline__ float gelu_exact(float x) {
    return 0.5f * x * (1.f + erff(x * 0.70710678118654752440f));
}
__device__ __forceinline__ unsigned short bf16_rne(float x) {
    unsigned u = __float_as_uint(x);
    return (unsigned short)((u + 0x7FFFu + ((u >> 16) & 1u)) >> 16);
}

// ---------------- CSR build ----------------

__global__ void k_hist(const int* __restrict__ dst, int* __restrict__ deg) {
    int e = blockIdx.x * 256 + threadIdx.x;
    atomicAdd(&deg[dst[e]], 1);
}

__global__ void k_scan1(const int* __restrict__ deg, int* __restrict__ rp, int* __restrict__ bsum) {
    __shared__ int s[256];
    int t = threadIdx.x;
    int i = blockIdx.x * 256 + t;
    int v = deg[i];
    s[t] = v;
    __syncthreads();
    #pragma unroll
    for (int off = 1; off < 256; off <<= 1) {
        int x = (t >= off) ? s[t - off] : 0;
        __syncthreads();
        s[t] += x;
        __syncthreads();
    }
    rp[i] = s[t] - v;
    if (t == 255) bsum[blockIdx.x] = s[t];
}

__global__ void k_scan2(const int* __restrict__ bsum, int* __restrict__ bscan, int* __restrict__ rp) {
    __shared__ int s[256];
    int t = threadIdx.x;
    int v = bsum[t];
    s[t] = v;
    __syncthreads();
    #pragma unroll
    for (int off = 1; off < 256; off <<= 1) {
        int x = (t >= off) ? s[t - off] : 0;
        __syncthreads();
        s[t] += x;
        __syncthreads();
    }
    bscan[t] = s[t] - v;
    if (t == 255) rp[NN] = s[t];
}

__global__ void k_scan3(int* __restrict__ rp, const int* __restrict__ bscan, int* __restrict__ cursor) {
    int i = blockIdx.x * 256 + threadIdx.x;
    int v = rp[i] + bscan[blockIdx.x];
    rp[i] = v;
    cursor[i] = v;
}

__global__ void k_scatter(const int* __restrict__ srcArr, const int* __restrict__ dstArr,
                          int* __restrict__ cursor, int* __restrict__ csr_src, int* __restrict__ csr_eid,
                          int* __restrict__ csr_dst, int* __restrict__ slot) {
    int e = blockIdx.x * 256 + threadIdx.x;
    int d = dstArr[e];
    int p = atomicAdd(&cursor[d], 1);
    csr_src[p] = srcArr[e];
    csr_eid[p] = e;
    csr_dst[p] = d;
    slot[e] = p;
}

// ---------------- edge-attr precompute ----------------

__global__ void k_wvec(const float* __restrict__ We, const float* __restrict__ ae, float* __restrict__ wvec) {
    int t = threadIdx.x;
    if (t < 3 * ED) {
        int l = t / ED, k = t % ED;
        const float* w = We + (long)(l * ED + k) * D;
        const float* a = ae + (long)l * D;
        float s = 0.f;
        #pragma unroll
        for (int i = 0; i < D; ++i) s += w[i] * a[i];
        wvec[t] = s;
    }
}

// ale_slot[l*NE + slot[e]] = dot(ea[e][:], wvec[l][:])  (CSR slot order)
__global__ void k_ale(const float* __restrict__ ea, const float* __restrict__ wvec,
                      const int* __restrict__ slot, float* __restrict__ ale) {
    int e = blockIdx.x * 256 + threadIdx.x;
    const float4* row = (const float4*)(ea + (long)e * ED);
    const float4* w0 = (const float4*)(wvec);
    const float4* w1 = (const float4*)(wvec + ED);
    const float4* w2 = (const float4*)(wvec + 2 * ED);
    float s0 = 0.f, s1 = 0.f, s2 = 0.f;
    #pragma unroll
    for (int i = 0; i < ED / 4; ++i) {
        float4 v = row[i];
        float4 a = w0[i], b = w1[i], c = w2[i];
        s0 += v.x * a.x + v.y * a.y + v.z * a.z + v.w * a.w;
        s1 += v.x * b.x + v.y * b.y + v.z * b.z + v.w * b.w;
        s2 += v.x * c.x + v.y * c.y + v.z * c.z + v.w * c.w;
    }
    int p = slot[e];
    ale[p] = s0;
    ale[NE + p] = s1;
    ale[2 * NE + p] = s2;
}

// ale_self[l*NN + n] = dot(mean incoming ea (0 if none), wvec[l])
__global__ void k_ale_self(const float* __restrict__ ea, const int* __restrict__ rp,
                           const int* __restrict__ csr_eid, const float* __restrict__ wvec,
                           float* __restrict__ ale_self) {
    int t = threadIdx.x;
    int n = blockIdx.x * 8 + (t >> 5);
    int lane = t & 31;
    int s = rp[n], e = rp[n + 1];
    float sum = 0.f;
    for (int j = s; j < e; ++j) {
        int eid = csr_eid[j];
        sum += ea[(long)eid * ED + lane];
    }
    int degn = e - s;
    float fill = (degn > 0) ? sum / (float)degn : 0.f;
    #pragma unroll
    for (int l = 0; l < 3; ++l) {
        float p = fill * wvec[l * ED + lane];
        #pragma unroll
        for (int off = 16; off > 0; off >>= 1) p += __shfl_xor(p, off);
        if (lane == 0) ale_self[l * NN + n] = p;
    }
}

// Pack W (128x128 fp32) into MFMA B-fragment order, split bf16 hi/lo.
// Element j of fragment (ks,q,n): W[ks*32+q*8+j][n], stored at ((ks*4+q)*128+n)*8+j.
__global__ void k_wpack(const float* __restrict__ Ws, short* __restrict__ Whp, short* __restrict__ Wlp) {
    int t = blockIdx.x * 256 + threadIdx.x;
    if (t >= 3 * 4 * 4 * 128) return;
    int n = t & 127;
    int q = (t >> 7) & 3;
    int ks = (t >> 9) & 3;
    int l = t >> 11;
    const float* w = Ws + (size_t)l * D * D;
    size_t obase = (size_t)l * D * D + ((size_t)((ks * 4 + q) * 128) + n) * 8;
    #pragma unroll
    for (int j = 0; j < 8; ++j) {
        float x = w[(size_t)(ks * 32 + q * 8 + j) * D + n];
        unsigned short hb = bf16_rne(x);
        float hf = __uint_as_float(((unsigned)hb) << 16);
        Whp[obase + j] = (short)hb;
        Wlp[obase + j] = (short)bf16_rne(x - hf);
    }
}

// ---------------- per-layer kernels ----------------

// C[64 x 128 per block] = A @ W via split-bf16 MFMA (hi*hi + hi*lo + lo*hi).
// 4 waves: wave covers rows (wave&1)*32..+31, cols (wave>>1)*64..+63.
// Epilogue: als[row] += sum(C[row]*a_s), ald likewise (atomicAdd, als/ald pre-zeroed).
__global__ __launch_bounds__(256) void k_gemm_mfma(const float* __restrict__ A,
        const short* __restrict__ Whp, const short* __restrict__ Wlp,
        const float* __restrict__ a_s, const float* __restrict__ a_d,
        float* __restrict__ C, float* __restrict__ als, float* __restrict__ ald) {
    int t = threadIdx.x;
    int wave = t >> 6, lane = t & 63;
    int l16 = lane & 15, q = lane >> 4;
    int rows_base = blockIdx.x * 64 + (wave & 1) * 32;
    int cols_base = (wave >> 1) * 64;

    f32x4 acc[2][4] = {};
    #pragma unroll
    for (int ks = 0; ks < 4; ++ks) {
        bf16x8 ah[2], alo[2];
        #pragma unroll
        for (int mt = 0; mt < 2; ++mt) {
            const float* ap = A + (size_t)(rows_base + mt * 16 + l16) * D + ks * 32 + q * 8;
            float4 f0 = *(const float4*)ap;
            float4 f1 = *(const float4*)(ap + 4);
            float xs[8] = {f0.x, f0.y, f0.z, f0.w, f1.x, f1.y, f1.z, f1.w};
            #pragma unroll
            for (int j = 0; j < 8; ++j) {
                unsigned short hb = bf16_rne(xs[j]);
                float hf = __uint_as_float(((unsigned)hb) << 16);
                ah[mt][j] = (short)hb;
                alo[mt][j] = (short)bf16_rne(xs[j] - hf);
            }
        }
        #pragma unroll
        for (int nt = 0; nt < 4; ++nt) {
            int n = cols_base + nt * 16 + l16;
            size_t idx = ((size_t)((ks * 4 + q) * 128) + n) * 8;
            bf16x8 bh = *(const bf16x8*)(Whp + idx);
            bf16x8 bl = *(const bf16x8*)(Wlp + idx);
            #pragma unroll
            for (int mt = 0; mt < 2; ++mt) {
                acc[mt][nt] = __builtin_amdgcn_mfma_f32_16x16x32_bf16(ah[mt], bh, acc[mt][nt], 0, 0, 0);
                acc[mt][nt] = __builtin_amdgcn_mfma_f32_16x16x32_bf16(ah[mt], bl, acc[mt][nt], 0, 0, 0);
                acc[mt][nt] = __builtin_amdgcn_mfma_f32_16x16x32_bf16(alo[mt], bh, acc[mt][nt], 0, 0, 0);
            }
        }
    }

    float as_r[4], ad_r[4];
    #pragma unroll
    for (int nt = 0; nt < 4; ++nt) {
        int col = cols_base + nt * 16 + l16;
        as_r[nt] = a_s[col];
        ad_r[nt] = a_d[col];
    }
    #pragma unroll
    for (int mt = 0; mt < 2; ++mt) {
        #pragma unroll
        for (int r = 0; r < 4; ++r) {
            int row = rows_base + mt * 16 + q * 4 + r;
            float ps = 0.f, pd = 0.f;
            #pragma unroll
            for (int nt = 0; nt < 4; ++nt) {
                float v = acc[mt][nt][r];
                ps += v * as_r[nt];
                pd += v * ad_r[nt];
                C[(size_t)row * D + cols_base + nt * 16 + l16] = v;
            }
            #pragma unroll
            for (int off = 8; off >= 1; off >>= 1) {
                ps += __shfl_xor(ps, off);
                pd += __shfl_xor(pd, off);
            }
            if (l16 == 0) {
                atomicAdd(&als[row], ps);
                atomicAdd(&ald[row], pd);
            }
        }
    }
}

// per-slot attention logit (CSR order, coalesced): al = leaky(als[src] + ald[dst] + ale_slot)
__global__ void k_alpass(const float* __restrict__ als, const float* __restrict__ ald,
                         const float* __restrict__ ale_slot, const int* __restrict__ csr_src,
                         const int* __restrict__ csr_dst, float* __restrict__ al_out) {
    int j = blockIdx.x * 256 + threadIdx.x;
    al_out[j] = leaky(als[csr_src[j]] + ald[csr_dst[j]] + ale_slot[j]);
}

// per-node segmented softmax stats; 16 lanes per node.
// alw: in = leaky logits per slot, out(in-place) = exp(al - m) (unnormalized).
__global__ __launch_bounds__(256) void k_norm(float* __restrict__ alw, const float* __restrict__ als,
                                              const float* __restrict__ ald, const float* __restrict__ ale_self,
                                              const int* __restrict__ rp, float* __restrict__ wself,
                                              float* __restrict__ invden) {
    int t = threadIdx.x;
    int lane16 = t & 15;
    int n = blockIdx.x * 16 + (t >> 4);
    int s = rp[n], e = rp[n + 1];
    float self_al = leaky(als[n] + ald[n] + ale_self[n]);
    float m = self_al;
    for (int base = s; base < e; base += 16) {
        int j = base + lane16;
        float v = (j < e) ? alw[j] : -1e30f;
        m = fmaxf(m, v);
    }
    #pragma unroll
    for (int off = 8; off >= 1; off >>= 1) m = fmaxf(m, __shfl_xor(m, off));
    float dpart = (lane16 == 0) ? __expf(self_al - m) : 0.f;
    for (int base = s; base < e; base += 16) {
        int j = base + lane16;
        if (j < e) {
            float ex = __expf(alw[j] - m);
            alw[j] = ex;
            dpart += ex;
        }
    }
    #pragma unroll
    for (int off = 8; off >= 1; off >>= 1) dpart += __shfl_xor(dpart, off);
    if (lane16 == 0) {
        wself[n] = __expf(self_al - m);
        invden[n] = 1.f / dpart;
    }
}

// weighted gather-accumulate; one wave per node, 2 cols per lane. No exp/shuffles.
__global__ __launch_bounds__(256) void k_aggr2(const float* __restrict__ h, const int* __restrict__ rp,
                                               const int* __restrict__ csr_src, const float* __restrict__ wslot,
                                               const float* __restrict__ wself, const float* __restrict__ invden,
                                               const float* __restrict__ bias, float* __restrict__ out) {
    int wave = threadIdx.x >> 6, lane = threadIdx.x & 63;
    int n = blockIdx.x * 4 + wave;
    int s = rp[n], e = rp[n + 1];
    float2 hv = ((const float2*)(h + (size_t)n * D))[lane];
    float wsf = wself[n];
    float ax = wsf * hv.x, ay = wsf * hv.y;
    for (int j = s; j < e; ++j) {
        int sn = csr_src[j];
        float w = wslot[j];
        float2 hs = ((const float2*)(h + (size_t)sn * D))[lane];
        ax += w * hs.x;
        ay += w * hs.y;
    }
    float inv = invden[n];
    float2 b2 = ((const float2*)bias)[lane];
    float ox = gelu_exact(ax * inv + b2.x);
    float oy = gelu_exact(ay * inv + b2.y);
    ((float2*)(out + (size_t)n * D))[lane] = make_float2(ox, oy);
}

// ---------------- launch ----------------

extern "C" void kernel_launch(void* const* d_in, const int* in_sizes, int n_in,
                              void* d_out, int out_size, void* d_ws, size_t ws_size,
                              hipStream_t stream) {
    (void)in_sizes; (void)n_in; (void)out_size; (void)ws_size;
    const float* x        = (const float*)d_in[0];
    const int*   eidx     = (const int*)d_in[1];   // [2, NE]: row0=src, row1=dst
    const float* ea       = (const float*)d_in[2];
    const float* Ws       = (const float*)d_in[3];
    const float* att_src  = (const float*)d_in[4];
    const float* att_dst  = (const float*)d_in[5];
    const float* W_edge   = (const float*)d_in[6];
    const float* att_edge = (const float*)d_in[7];
    const float* bias     = (const float*)d_in[8];
    float* out = (float*)d_out;

    char* ws = (char*)d_ws;
    size_t off = 0;
    auto alloc = [&](size_t bytes) {
        void* p = ws + off;
        off += (bytes + 255) & ~(size_t)255;
        return p;
    };
    float* B0       = (float*)alloc((size_t)NN * D * 4);   // h after GEMM
    float* als      = (float*)alloc((size_t)NN * 4);
    float* ald      = (float*)alloc((size_t)NN * 4);
    float* ale      = (float*)alloc((size_t)3 * NE * 4);   // slot-ordered, per layer
    float* ale_self = (float*)alloc((size_t)3 * NN * 4);
    float* wvec     = (float*)alloc(3 * ED * 4);
    int*   deg      = (int*)alloc((size_t)NN * 4);
    int*   rp       = (int*)alloc((size_t)(NN + 4) * 4);
    int*   cursor   = (int*)alloc((size_t)NN * 4);
    int*   bsum     = (int*)alloc(256 * 4);
    int*   bscan    = (int*)alloc(256 * 4);
    int*   csr_src  = (int*)alloc((size_t)NE * 4);
    int*   csr_eid  = (int*)alloc((size_t)NE * 4);
    int*   csr_dst  = (int*)alloc((size_t)NE * 4);
    float* alw      = (float*)alloc((size_t)NE * 4);       // logits -> unnormalized weights
    int*   slot     = (int*)alloc((size_t)NE * 4);
    float* wself    = (float*)alloc((size_t)NN * 4);
    float* invden   = (float*)alloc((size_t)NN * 4);
    short* Whp      = (short*)alloc((size_t)3 * D * D * 2);
    short* Wlp      = (short*)alloc((size_t)3 * D * D * 2);

    const int* e_src = eidx;
    const int* e_dst = eidx + NE;

    // CSR build
    hipMemsetAsync(deg, 0, (size_t)NN * 4, stream);
    k_hist<<<NE / 256, 256, 0, stream>>>(e_dst, deg);
    k_scan1<<<NN / 256, 256, 0, stream>>>(deg, rp, bsum);
    k_scan2<<<1, 256, 0, stream>>>(bsum, bscan, rp);
    k_scan3<<<NN / 256, 256, 0, stream>>>(rp, bscan, cursor);
    k_scatter<<<NE / 256, 256, 0, stream>>>(e_src, e_dst, cursor, csr_src, csr_eid, csr_dst, slot);

    // edge-attr + weight precompute (shared across layers)
    k_wvec<<<1, 128, 0, stream>>>(W_edge, att_edge, wvec);
    k_ale<<<NE / 256, 256, 0, stream>>>(ea, wvec, slot, ale);
    k_ale_self<<<NN / 8, 256, 0, stream>>>(ea, rp, csr_eid, wvec, ale_self);
    k_wpack<<<24, 256, 0, stream>>>(Ws, Whp, Wlp);

    // layers; d_out doubles as the h ping-pong buffer
    const float* hin = x;
    for (int l = 0; l < 3; ++l) {
        hipMemsetAsync(als, 0, (size_t)NN * 4, stream);
        hipMemsetAsync(ald, 0, (size_t)NN * 4, stream);
        k_gemm_mfma<<<NN / 64, 256, 0, stream>>>(hin, Whp + (size_t)l * D * D, Wlp + (size_t)l * D * D,
                                                 att_src + (size_t)l * D, att_dst + (size_t)l * D,
                                                 B0, als, ald);
        k_alpass<<<NE / 256, 256, 0, stream>>>(als, ald, ale + (size_t)l * NE, csr_src, csr_dst, alw);
        k_norm<<<NN / 16, 256, 0, stream>>>(alw, als, ald, ale_self + (size_t)l * NN, rp, wself, invden);
        k_aggr2<<<NN / 4, 256, 0, stream>>>(B0, rp, csr_src, alw, wself, invden,
                                            bias + (size_t)l * D, out);
        hin = out;
    }
}

// Round 3
// 440.842 us; speedup vs baseline: 1.4160x; 1.3218x over previous
//
#include <hip/hip_runtime.h>
#include <math.h>

#define NN 65536        // nodes
#define NE 524288       // edges (without self loops)
#define D 128
#define ED 32
#define NEG_SLOPE 0.2f

typedef short bf16x8 __attribute__((ext_vector_type(8)));
typedef float f32x4 __attribute__((ext_vector_type(4)));

__device__ __forceinline__ float leaky(float x) { return x > 0.f ? x : NEG_SLOPE * x; }
__device__ __forceinline__ float gelu_exact(float x) {
    return 0.5f * x * (1.f + erff(x * 0.70710678118654752440f));
}
__device__ __forceinline__ unsigned short bf16_rne(float x) {
    unsigned u = __float_as_uint(x);
    return (unsigned short)((u + 0x7FFFu + ((u >> 16) & 1u)) >> 16);
}

// ---------------- CSR build ----------------

__global__ void k_hist(const int* __restrict__ dst, int* __restrict__ deg) {
    int e = blockIdx.x * 256 + threadIdx.x;
    atomicAdd(&deg[dst[e]], 1);
}

__global__ void k_scan1(const int* __restrict__ deg, int* __restrict__ rp, int* __restrict__ bsum) {
    __shared__ int s[256];
    int t = threadIdx.x;
    int i = blockIdx.x * 256 + t;
    int v = deg[i];
    s[t] = v;
    __syncthreads();
    #pragma unroll
    for (int off = 1; off < 256; off <<= 1) {
        int x = (t >= off) ? s[t - off] : 0;
        __syncthreads();
        s[t] += x;
        __syncthreads();
    }
    rp[i] = s[t] - v;
    if (t == 255) bsum[blockIdx.x] = s[t];
}

__global__ void k_scan2(const int* __restrict__ bsum, int* __restrict__ bscan, int* __restrict__ rp) {
    __shared__ int s[256];
    int t = threadIdx.x;
    int v = bsum[t];
    s[t] = v;
    __syncthreads();
    #pragma unroll
    for (int off = 1; off < 256; off <<= 1) {
        int x = (t >= off) ? s[t - off] : 0;
        __syncthreads();
        s[t] += x;
        __syncthreads();
    }
    bscan[t] = s[t] - v;
    if (t == 255) rp[NN] = s[t];
}

__global__ void k_scan3(int* __restrict__ rp, const int* __restrict__ bscan, int* __restrict__ cursor) {
    int i = blockIdx.x * 256 + threadIdx.x;
    int v = rp[i] + bscan[blockIdx.x];
    rp[i] = v;
    cursor[i] = v;
}

__global__ void k_scatter(const int* __restrict__ srcArr, const int* __restrict__ dstArr,
                          int* __restrict__ cursor, int* __restrict__ csr_src, int* __restrict__ slot) {
    int e = blockIdx.x * 256 + threadIdx.x;
    int d = dstArr[e];
    int p = atomicAdd(&cursor[d], 1);
    csr_src[p] = srcArr[e];
    slot[e] = p;
}

// ---------------- edge-attr precompute ----------------

__global__ void k_wvec(const float* __restrict__ We, const float* __restrict__ ae, float* __restrict__ wvec) {
    int t = threadIdx.x;
    if (t < 3 * ED) {
        int l = t / ED, k = t % ED;
        const float* w = We + (long)(l * ED + k) * D;
        const float* a = ae + (long)l * D;
        float s = 0.f;
        #pragma unroll
        for (int i = 0; i < D; ++i) s += w[i] * a[i];
        wvec[t] = s;
    }
}

// ale_slot[l*NE + slot[e]] = dot(ea[e][:], wvec[l][:])  (CSR slot order)
__global__ void k_ale(const float* __restrict__ ea, const float* __restrict__ wvec,
                      const int* __restrict__ slot, float* __restrict__ ale) {
    int e = blockIdx.x * 256 + threadIdx.x;
    const float4* row = (const float4*)(ea + (long)e * ED);
    const float4* w0 = (const float4*)(wvec);
    const float4* w1 = (const float4*)(wvec + ED);
    const float4* w2 = (const float4*)(wvec + 2 * ED);
    float s0 = 0.f, s1 = 0.f, s2 = 0.f;
    #pragma unroll
    for (int i = 0; i < ED / 4; ++i) {
        float4 v = row[i];
        float4 a = w0[i], b = w1[i], c = w2[i];
        s0 += v.x * a.x + v.y * a.y + v.z * a.z + v.w * a.w;
        s1 += v.x * b.x + v.y * b.y + v.z * b.z + v.w * b.w;
        s2 += v.x * c.x + v.y * c.y + v.z * c.z + v.w * c.w;
    }
    int p = slot[e];
    ale[p] = s0;
    ale[NE + p] = s1;
    ale[2 * NE + p] = s2;
}

// Pack W (128x128 fp32) into MFMA B-fragment order, split bf16 hi/lo.
// Element j of fragment (ks,q,n): W[ks*32+q*8+j][n], stored at ((ks*4+q)*128+n)*8+j.
__global__ void k_wpack(const float* __restrict__ Ws, short* __restrict__ Whp, short* __restrict__ Wlp) {
    int t = blockIdx.x * 256 + threadIdx.x;
    if (t >= 3 * 4 * 4 * 128) return;
    int n = t & 127;
    int q = (t >> 7) & 3;
    int ks = (t >> 9) & 3;
    int l = t >> 11;
    const float* w = Ws + (size_t)l * D * D;
    size_t obase = (size_t)l * D * D + ((size_t)((ks * 4 + q) * 128) + n) * 8;
    #pragma unroll
    for (int j = 0; j < 8; ++j) {
        float x = w[(size_t)(ks * 32 + q * 8 + j) * D + n];
        unsigned short hb = bf16_rne(x);
        float hf = __uint_as_float(((unsigned)hb) << 16);
        Whp[obase + j] = (short)hb;
        Wlp[obase + j] = (short)bf16_rne(x - hf);
    }
}

// ---------------- per-layer kernels ----------------

// C[64 x 128 per block] = A @ W via split-bf16 MFMA. One wave = 16 rows x 128 cols
// (A read once, conversion once). Epilogue writes als/ald directly (no atomics).
__global__ __launch_bounds__(256) void k_gemm_mfma(const float* __restrict__ A,
        const short* __restrict__ Whp, const short* __restrict__ Wlp,
        const float* __restrict__ a_s, const float* __restrict__ a_d,
        float* __restrict__ C, float* __restrict__ als, float* __restrict__ ald) {
    int t = threadIdx.x;
    int wave = t >> 6, lane = t & 63;
    int l16 = lane & 15, q = lane >> 4;
    int row0 = blockIdx.x * 64 + wave * 16;

    f32x4 acc[8] = {};
    #pragma unroll
    for (int ks = 0; ks < 4; ++ks) {
        const float* ap = A + (size_t)(row0 + l16) * D + ks * 32 + q * 8;
        float4 f0 = *(const float4*)ap;
        float4 f1 = *(const float4*)(ap + 4);
        float xs[8] = {f0.x, f0.y, f0.z, f0.w, f1.x, f1.y, f1.z, f1.w};
        bf16x8 ah, alo;
        #pragma unroll
        for (int j = 0; j < 8; ++j) {
            unsigned short hb = bf16_rne(xs[j]);
            float hf = __uint_as_float(((unsigned)hb) << 16);
            ah[j] = (short)hb;
            alo[j] = (short)bf16_rne(xs[j] - hf);
        }
        #pragma unroll
        for (int nt = 0; nt < 8; ++nt) {
            size_t idx = ((size_t)((ks * 4 + q) * 128) + nt * 16 + l16) * 8;
            bf16x8 bh = *(const bf16x8*)(Whp + idx);
            bf16x8 bl = *(const bf16x8*)(Wlp + idx);
            acc[nt] = __builtin_amdgcn_mfma_f32_16x16x32_bf16(ah, bh, acc[nt], 0, 0, 0);
            acc[nt] = __builtin_amdgcn_mfma_f32_16x16x32_bf16(ah, bl, acc[nt], 0, 0, 0);
            acc[nt] = __builtin_amdgcn_mfma_f32_16x16x32_bf16(alo, bh, acc[nt], 0, 0, 0);
        }
    }

    float as_r[8], ad_r[8];
    #pragma unroll
    for (int nt = 0; nt < 8; ++nt) {
        int col = nt * 16 + l16;
        as_r[nt] = a_s[col];
        ad_r[nt] = a_d[col];
    }
    #pragma unroll
    for (int r = 0; r < 4; ++r) {
        int row = row0 + q * 4 + r;
        float ps = 0.f, pd = 0.f;
        #pragma unroll
        for (int nt = 0; nt < 8; ++nt) {
            float v = acc[nt][r];
            ps += v * as_r[nt];
            pd += v * ad_r[nt];
            C[(size_t)row * D + nt * 16 + l16] = v;
        }
        #pragma unroll
        for (int off = 8; off >= 1; off >>= 1) {
            ps += __shfl_xor(ps, off);
            pd += __shfl_xor(pd, off);
        }
        if (l16 == 0) {
            als[row] = ps;
            ald[row] = pd;
        }
    }
}

// Fused attention softmax + weighted gather. One wave per dst node.
// Pass A: lanes load their edge (csr_src, ale, als[src]) in parallel; cross-lane
// reduce (max, den) and the ale mean (= self-loop ale term, since dot is linear).
// Pass B: per-lane weights, gather h rows 4-at-a-time (independent loads for MLP).
__global__ __launch_bounds__(256) void k_aggr_fused(const float* __restrict__ h,
        const float* __restrict__ als, const float* __restrict__ ald,
        const float* __restrict__ ale, const int* __restrict__ rp,
        const int* __restrict__ csr_src, const float* __restrict__ bias,
        float* __restrict__ out) {
    int wave = threadIdx.x >> 6, lane = threadIdx.x & 63;
    int n = blockIdx.x * 4 + wave;
    int s = rp[n], e = rp[n + 1];
    int deg = e - s;
    float aldd = ald[n];
    float alsn = als[n];

    // ---- pass A: online (m, den) + ale sum ----
    float m = -1e30f, den = 0.f, ale_sum = 0.f;
    int sn0 = 0;
    float al0 = -1e30f;
    for (int base = s; base < e; base += 64) {
        int j = base + lane;
        bool v = j < e;
        int sn = v ? csr_src[j] : 0;
        float alev = v ? ale[j] : 0.f;
        float al = v ? leaky(als[sn] + aldd + alev) : -1e30f;
        if (base == s) { sn0 = sn; al0 = al; }
        ale_sum += alev;
        float mn = fmaxf(m, al);
        den = den * __expf(m - mn) + (v ? __expf(al - mn) : 0.f);
        m = mn;
    }
    #pragma unroll
    for (int off = 1; off < 64; off <<= 1) {
        float mo = __shfl_xor(m, off);
        float dno = __shfl_xor(den, off);
        float as_ = __shfl_xor(ale_sum, off);
        float mn = fmaxf(m, mo);
        den = den * __expf(m - mn) + dno * __expf(mo - mn);
        m = mn;
        ale_sum += as_;
    }
    float inv_deg = (deg > 0) ? 1.f / (float)deg : 0.f;
    float self_al = leaky(alsn + aldd + ale_sum * inv_deg);
    {
        float mn = fmaxf(m, self_al);
        den = den * __expf(m - mn) + __expf(self_al - mn);
        m = mn;
    }
    float inv = 1.f / den;
    float wself = __expf(self_al - m) * inv;

    // ---- pass B: weighted gather ----
    float2 hv = ((const float2*)(h + (size_t)n * D))[lane];
    float ax = wself * hv.x, ay = wself * hv.y;
    for (int base = s; base < e; base += 64) {
        int cnt = min(e - base, 64);
        int sn;
        float w;
        if (base == s && deg <= 64) {
            sn = sn0;
            w = (lane < cnt) ? __expf(al0 - m) * inv : 0.f;
        } else {
            int j = base + lane;
            if (lane < cnt) {
                sn = csr_src[j];
                w = __expf(leaky(als[sn] + aldd + ale[j]) - m) * inv;
            } else {
                sn = 0;
                w = 0.f;
            }
        }
        int t = 0;
        for (; t + 4 <= cnt; t += 4) {
            int s0 = __shfl(sn, t), s1 = __shfl(sn, t + 1), s2 = __shfl(sn, t + 2), s3 = __shfl(sn, t + 3);
            float w0 = __shfl(w, t), w1 = __shfl(w, t + 1), w2 = __shfl(w, t + 2), w3 = __shfl(w, t + 3);
            float2 h0 = ((const float2*)(h + (size_t)s0 * D))[lane];
            float2 h1 = ((const float2*)(h + (size_t)s1 * D))[lane];
            float2 h2 = ((const float2*)(h + (size_t)s2 * D))[lane];
            float2 h3 = ((const float2*)(h + (size_t)s3 * D))[lane];
            ax += w0 * h0.x + w1 * h1.x + w2 * h2.x + w3 * h3.x;
            ay += w0 * h0.y + w1 * h1.y + w2 * h2.y + w3 * h3.y;
        }
        for (; t < cnt; ++t) {
            int st = __shfl(sn, t);
            float wt = __shfl(w, t);
            float2 ht = ((const float2*)(h + (size_t)st * D))[lane];
            ax += wt * ht.x;
            ay += wt * ht.y;
        }
    }
    float2 b2 = ((const float2*)bias)[lane];
    float ox = gelu_exact(ax + b2.x);
    float oy = gelu_exact(ay + b2.y);
    ((float2*)(out + (size_t)n * D))[lane] = make_float2(ox, oy);
}

// ---------------- launch ----------------

extern "C" void kernel_launch(void* const* d_in, const int* in_sizes, int n_in,
                              void* d_out, int out_size, void* d_ws, size_t ws_size,
                              hipStream_t stream) {
    (void)in_sizes; (void)n_in; (void)out_size; (void)ws_size;
    const float* x        = (const float*)d_in[0];
    const int*   eidx     = (const int*)d_in[1];   // [2, NE]: row0=src, row1=dst
    const float* ea       = (const float*)d_in[2];
    const float* Ws       = (const float*)d_in[3];
    const float* att_src  = (const float*)d_in[4];
    const float* att_dst  = (const float*)d_in[5];
    const float* W_edge   = (const float*)d_in[6];
    const float* att_edge = (const float*)d_in[7];
    const float* bias     = (const float*)d_in[8];
    float* out = (float*)d_out;

    char* ws = (char*)d_ws;
    size_t off = 0;
    auto alloc = [&](size_t bytes) {
        void* p = ws + off;
        off += (bytes + 255) & ~(size_t)255;
        return p;
    };
    float* B0      = (float*)alloc((size_t)NN * D * 4);   // h after GEMM
    float* als     = (float*)alloc((size_t)NN * 4);
    float* ald     = (float*)alloc((size_t)NN * 4);
    float* ale     = (float*)alloc((size_t)3 * NE * 4);   // slot-ordered, per layer
    float* wvec    = (float*)alloc(3 * ED * 4);
    int*   deg     = (int*)alloc((size_t)NN * 4);
    int*   rp      = (int*)alloc((size_t)(NN + 4) * 4);
    int*   cursor  = (int*)alloc((size_t)NN * 4);
    int*   bsum    = (int*)alloc(256 * 4);
    int*   bscan   = (int*)alloc(256 * 4);
    int*   csr_src = (int*)alloc((size_t)NE * 4);
    int*   slot    = (int*)alloc((size_t)NE * 4);
    short* Whp     = (short*)alloc((size_t)3 * D * D * 2);
    short* Wlp     = (short*)alloc((size_t)3 * D * D * 2);

    const int* e_src = eidx;
    const int* e_dst = eidx + NE;

    // CSR build
    hipMemsetAsync(deg, 0, (size_t)NN * 4, stream);
    k_hist<<<NE / 256, 256, 0, stream>>>(e_dst, deg);
    k_scan1<<<NN / 256, 256, 0, stream>>>(deg, rp, bsum);
    k_scan2<<<1, 256, 0, stream>>>(bsum, bscan, rp);
    k_scan3<<<NN / 256, 256, 0, stream>>>(rp, bscan, cursor);
    k_scatter<<<NE / 256, 256, 0, stream>>>(e_src, e_dst, cursor, csr_src, slot);

    // edge-attr + weight precompute (shared across layers)
    k_wvec<<<1, 128, 0, stream>>>(W_edge, att_edge, wvec);
    k_ale<<<NE / 256, 256, 0, stream>>>(ea, wvec, slot, ale);
    k_wpack<<<24, 256, 0, stream>>>(Ws, Whp, Wlp);

    // layers; d_out doubles as the h ping-pong buffer
    const float* hin = x;
    for (int l = 0; l < 3; ++l) {
        k_gemm_mfma<<<NN / 64, 256, 0, stream>>>(hin, Whp + (size_t)l * D * D, Wlp + (size_t)l * D * D,
                                                 att_src + (size_t)l * D, att_dst + (size_t)l * D,
                                                 B0, als, ald);
        k_aggr_fused<<<NN / 4, 256, 0, stream>>>(B0, als, ald, ale + (size_t)l * NE,
                                                 rp, csr_src, bias + (size_t)l * D, out);
        hin = out;
    }
}

// Round 4
// 423.197 us; speedup vs baseline: 1.4751x; 1.0417x over previous
//
#include <hip/hip_runtime.h>
#include <math.h>

#define NN 65536        // nodes
#define NE 524288       // edges (without self loops)
#define D 128
#define ED 32
#define NEG_SLOPE 0.2f

typedef short bf16x8 __attribute__((ext_vector_type(8)));
typedef float f32x4 __attribute__((ext_vector_type(4)));

__device__ __forceinline__ float leaky(float x) { return x > 0.f ? x : NEG_SLOPE * x; }
__device__ __forceinline__ float gelu_exact(float x) {
    return 0.5f * x * (1.f + erff(x * 0.70710678118654752440f));
}
__device__ __forceinline__ unsigned short bf16_rne(float x) {
    unsigned u = __float_as_uint(x);
    return (unsigned short)((u + 0x7FFFu + ((u >> 16) & 1u)) >> 16);
}

// ---------------- CSR build ----------------

__global__ void k_hist(const int* __restrict__ dst, int* __restrict__ deg) {
    int e = blockIdx.x * 256 + threadIdx.x;
    atomicAdd(&deg[dst[e]], 1);
}

__global__ void k_scan1(const int* __restrict__ deg, int* __restrict__ rp, int* __restrict__ bsum) {
    __shared__ int s[256];
    int t = threadIdx.x;
    int i = blockIdx.x * 256 + t;
    int v = deg[i];
    s[t] = v;
    __syncthreads();
    #pragma unroll
    for (int off = 1; off < 256; off <<= 1) {
        int x = (t >= off) ? s[t - off] : 0;
        __syncthreads();
        s[t] += x;
        __syncthreads();
    }
    rp[i] = s[t] - v;
    if (t == 255) bsum[blockIdx.x] = s[t];
}

__global__ void k_scan2(const int* __restrict__ bsum, int* __restrict__ bscan, int* __restrict__ rp) {
    __shared__ int s[256];
    int t = threadIdx.x;
    int v = bsum[t];
    s[t] = v;
    __syncthreads();
    #pragma unroll
    for (int off = 1; off < 256; off <<= 1) {
        int x = (t >= off) ? s[t - off] : 0;
        __syncthreads();
        s[t] += x;
        __syncthreads();
    }
    bscan[t] = s[t] - v;
    if (t == 255) rp[NN] = s[t];
}

__global__ void k_scan3(int* __restrict__ rp, const int* __restrict__ bscan, int* __restrict__ cursor) {
    int i = blockIdx.x * 256 + threadIdx.x;
    int v = rp[i] + bscan[blockIdx.x];
    rp[i] = v;
    cursor[i] = v;
}

// ---------------- edge precompute ----------------

__global__ void k_wvec(const float* __restrict__ We, const float* __restrict__ ae, float* __restrict__ wvec) {
    int t = threadIdx.x;
    if (t < 3 * ED) {
        int l = t / ED, k = t % ED;
        const float* w = We + (long)(l * ED + k) * D;
        const float* a = ae + (long)l * D;
        float s = 0.f;
        #pragma unroll
        for (int i = 0; i < D; ++i) s += w[i] * a[i];
        wvec[t] = s;
    }
}

// Fused scatter + ale: one packed record per CSR slot: (src, ale_l0, ale_l1, ale_l2)
__global__ void k_scatter_ale(const int* __restrict__ srcArr, const int* __restrict__ dstArr,
                              int* __restrict__ cursor, const float* __restrict__ ea,
                              const float* __restrict__ wvec, int4* __restrict__ edata) {
    int e = blockIdx.x * 256 + threadIdx.x;
    int d = dstArr[e];
    int p = atomicAdd(&cursor[d], 1);
    const float4* row = (const float4*)(ea + (long)e * ED);
    const float4* w0 = (const float4*)(wvec);
    const float4* w1 = (const float4*)(wvec + ED);
    const float4* w2 = (const float4*)(wvec + 2 * ED);
    float s0 = 0.f, s1 = 0.f, s2 = 0.f;
    #pragma unroll
    for (int i = 0; i < ED / 4; ++i) {
        float4 v = row[i];
        float4 a = w0[i], b = w1[i], c = w2[i];
        s0 += v.x * a.x + v.y * a.y + v.z * a.z + v.w * a.w;
        s1 += v.x * b.x + v.y * b.y + v.z * b.z + v.w * b.w;
        s2 += v.x * c.x + v.y * c.y + v.z * c.z + v.w * c.w;
    }
    edata[p] = make_int4(srcArr[e], __float_as_int(s0), __float_as_int(s1), __float_as_int(s2));
}

// Pack W (128x128 fp32) into MFMA B-fragment order, split bf16 hi/lo.
__global__ void k_wpack(const float* __restrict__ Ws, short* __restrict__ Whp, short* __restrict__ Wlp) {
    int t = blockIdx.x * 256 + threadIdx.x;
    if (t >= 3 * 4 * 4 * 128) return;
    int n = t & 127;
    int q = (t >> 7) & 3;
    int ks = (t >> 9) & 3;
    int l = t >> 11;
    const float* w = Ws + (size_t)l * D * D;
    size_t obase = (size_t)l * D * D + ((size_t)((ks * 4 + q) * 128) + n) * 8;
    #pragma unroll
    for (int j = 0; j < 8; ++j) {
        float x = w[(size_t)(ks * 32 + q * 8 + j) * D + n];
        unsigned short hb = bf16_rne(x);
        float hf = __uint_as_float(((unsigned)hb) << 16);
        Whp[obase + j] = (short)hb;
        Wlp[obase + j] = (short)bf16_rne(x - hf);
    }
}

// Split fp32 x into bf16 hi/lo (row-major), for layer-0 GEMM A.
__global__ void k_splitx(const float* __restrict__ x, unsigned short* __restrict__ Hh,
                         unsigned short* __restrict__ Hl) {
    int i = blockIdx.x * 256 + threadIdx.x;   // per float4
    float4 v = ((const float4*)x)[i];
    float xs[4] = {v.x, v.y, v.z, v.w};
    ushort4 h, l;
    unsigned short* hp = (unsigned short*)&h;
    unsigned short* lp = (unsigned short*)&l;
    #pragma unroll
    for (int j = 0; j < 4; ++j) {
        unsigned short hb = bf16_rne(xs[j]);
        float hf = __uint_as_float(((unsigned)hb) << 16);
        hp[j] = hb;
        lp[j] = bf16_rne(xs[j] - hf);
    }
    ((ushort4*)Hh)[i] = h;
    ((ushort4*)Hl)[i] = l;
}

// ---------------- per-layer kernels ----------------

// C[128 x 128 per block] = A @ W via split-bf16 MFMA. A pre-split (bf16 hi/lo).
// One wave = 32 rows x 128 cols. Epilogue writes als/ald directly.
__global__ __launch_bounds__(256) void k_gemm_mfma(const unsigned short* __restrict__ Ah,
        const unsigned short* __restrict__ Al,
        const short* __restrict__ Whp, const short* __restrict__ Wlp,
        const float* __restrict__ a_s, const float* __restrict__ a_d,
        float* __restrict__ C, float* __restrict__ als, float* __restrict__ ald) {
    int t = threadIdx.x;
    int wave = t >> 6, lane = t & 63;
    int l16 = lane & 15, q = lane >> 4;
    int rows_base = blockIdx.x * 128 + wave * 32;

    f32x4 acc[2][8] = {};
    #pragma unroll
    for (int ks = 0; ks < 4; ++ks) {
        bf16x8 ah[2], alo[2];
        #pragma unroll
        for (int mt = 0; mt < 2; ++mt) {
            size_t abase = (size_t)(rows_base + mt * 16 + l16) * D + ks * 32 + q * 8;
            ah[mt]  = *(const bf16x8*)(Ah + abase);
            alo[mt] = *(const bf16x8*)(Al + abase);
        }
        #pragma unroll
        for (int nt = 0; nt < 8; ++nt) {
            size_t idx = ((size_t)((ks * 4 + q) * 128) + nt * 16 + l16) * 8;
            bf16x8 bh = *(const bf16x8*)(Whp + idx);
            bf16x8 bl = *(const bf16x8*)(Wlp + idx);
            #pragma unroll
            for (int mt = 0; mt < 2; ++mt) {
                acc[mt][nt] = __builtin_amdgcn_mfma_f32_16x16x32_bf16(ah[mt], bh, acc[mt][nt], 0, 0, 0);
                acc[mt][nt] = __builtin_amdgcn_mfma_f32_16x16x32_bf16(ah[mt], bl, acc[mt][nt], 0, 0, 0);
                acc[mt][nt] = __builtin_amdgcn_mfma_f32_16x16x32_bf16(alo[mt], bh, acc[mt][nt], 0, 0, 0);
            }
        }
    }

    float as_r[8], ad_r[8];
    #pragma unroll
    for (int nt = 0; nt < 8; ++nt) {
        int col = nt * 16 + l16;
        as_r[nt] = a_s[col];
        ad_r[nt] = a_d[col];
    }
    #pragma unroll
    for (int mt = 0; mt < 2; ++mt) {
        #pragma unroll
        for (int r = 0; r < 4; ++r) {
            int row = rows_base + mt * 16 + q * 4 + r;
            float ps = 0.f, pd = 0.f;
            #pragma unroll
            for (int nt = 0; nt < 8; ++nt) {
                float v = acc[mt][nt][r];
                ps += v * as_r[nt];
                pd += v * ad_r[nt];
                C[(size_t)row * D + nt * 16 + l16] = v;
            }
            #pragma unroll
            for (int off = 8; off >= 1; off >>= 1) {
                ps += __shfl_xor(ps, off);
                pd += __shfl_xor(pd, off);
            }
            if (l16 == 0) {
                als[row] = ps;
                ald[row] = pd;
            }
        }
    }
}

// Fused softmax + weighted gather. One wave per dst node.
// Fast path deg<=64: one packed edata load/lane, combined max/ale-sum butterfly,
// 2 exps/lane, gather unrolled x8. Mid layers emit split-bf16 h for the next GEMM.
__global__ __launch_bounds__(256) void k_aggr_fused(const float* __restrict__ h,
        const float* __restrict__ als, const float* __restrict__ ald,
        const int4* __restrict__ edata, const int* __restrict__ rp,
        const float* __restrict__ bias, int lsel, float* __restrict__ out_f32,
        unsigned* __restrict__ out_hi, unsigned* __restrict__ out_lo) {
    int wave = threadIdx.x >> 6, lane = threadIdx.x & 63;
    int n = blockIdx.x * 4 + wave;
    int s = rp[n], e = rp[n + 1];
    int deg = e - s;
    float aldd = ald[n];
    float alsn = als[n];
    float inv_deg = (deg > 0) ? 1.f / (float)deg : 0.f;

    float2 hv = ((const float2*)(h + (size_t)n * D))[lane];
    float ax, ay;

    if (deg <= 64) {
        int sn0 = 0;
        float al0 = -1e30f, alev0 = 0.f;
        if (lane < deg) {
            int4 ed = edata[s + lane];
            sn0 = ed.x;
            int ai = (lsel == 0) ? ed.y : ((lsel == 1) ? ed.z : ed.w);
            alev0 = __int_as_float(ai);
            al0 = leaky(als[sn0] + aldd + alev0);
        }
        float m = al0, asum = alev0;
        #pragma unroll
        for (int off = 1; off < 64; off <<= 1) {
            m = fmaxf(m, __shfl_xor(m, off));
            asum += __shfl_xor(asum, off);
        }
        float self_al = leaky(alsn + aldd + asum * inv_deg);
        m = fmaxf(m, self_al);
        float p0 = (lane < deg) ? __expf(al0 - m) : 0.f;
        float den = p0;
        #pragma unroll
        for (int off = 1; off < 64; off <<= 1) den += __shfl_xor(den, off);
        float es = __expf(self_al - m);
        den += es;
        float inv = 1.f / den;
        float w0 = p0 * inv;
        float wself = es * inv;

        ax = wself * hv.x;
        ay = wself * hv.y;
        int t = 0;
        for (; t + 8 <= deg; t += 8) {
            int   sA = __shfl(sn0, t),     sB = __shfl(sn0, t + 1), sC = __shfl(sn0, t + 2), sD = __shfl(sn0, t + 3);
            int   sE = __shfl(sn0, t + 4), sF = __shfl(sn0, t + 5), sG = __shfl(sn0, t + 6), sH = __shfl(sn0, t + 7);
            float wA = __shfl(w0, t),      wB = __shfl(w0, t + 1),  wC = __shfl(w0, t + 2),  wD = __shfl(w0, t + 3);
            float wE = __shfl(w0, t + 4),  wF = __shfl(w0, t + 5),  wG = __shfl(w0, t + 6),  wH = __shfl(w0, t + 7);
            float2 hA = ((const float2*)(h + (size_t)sA * D))[lane];
            float2 hB = ((const float2*)(h + (size_t)sB * D))[lane];
            float2 hC = ((const float2*)(h + (size_t)sC * D))[lane];
            float2 hD = ((const float2*)(h + (size_t)sD * D))[lane];
            float2 hE = ((const float2*)(h + (size_t)sE * D))[lane];
            float2 hF = ((const float2*)(h + (size_t)sF * D))[lane];
            float2 hG = ((const float2*)(h + (size_t)sG * D))[lane];
            float2 hH = ((const float2*)(h + (size_t)sH * D))[lane];
            ax += wA * hA.x + wB * hB.x + wC * hC.x + wD * hD.x + wE * hE.x + wF * hF.x + wG * hG.x + wH * hH.x;
            ay += wA * hA.y + wB * hB.y + wC * hC.y + wD * hD.y + wE * hE.y + wF * hF.y + wG * hG.y + wH * hH.y;
        }
        for (; t + 4 <= deg; t += 4) {
            int   sA = __shfl(sn0, t), sB = __shfl(sn0, t + 1), sC = __shfl(sn0, t + 2), sD = __shfl(sn0, t + 3);
            float wA = __shfl(w0, t),  wB = __shfl(w0, t + 1),  wC = __shfl(w0, t + 2),  wD = __shfl(w0, t + 3);
            float2 hA = ((const float2*)(h + (size_t)sA * D))[lane];
            float2 hB = ((const float2*)(h + (size_t)sB * D))[lane];
            float2 hC = ((const float2*)(h + (size_t)sC * D))[lane];
            float2 hD = ((const float2*)(h + (size_t)sD * D))[lane];
            ax += wA * hA.x + wB * hB.x + wC * hC.x + wD * hD.x;
            ay += wA * hA.y + wB * hB.y + wC * hC.y + wD * hD.y;
        }
        for (; t < deg; ++t) {
            int st = __shfl(sn0, t);
            float wt = __shfl(w0, t);
            float2 ht = ((const float2*)(h + (size_t)st * D))[lane];
            ax += wt * ht.x;
            ay += wt * ht.y;
        }
    } else {
        // general path (rare): 3-pass with recompute
        float m = -1e30f, asum = 0.f;
        for (int base = s; base < e; base += 64) {
            int j = base + lane;
            if (j < e) {
                int4 ed = edata[j];
                int ai = (lsel == 0) ? ed.y : ((lsel == 1) ? ed.z : ed.w);
                float alev = __int_as_float(ai);
                asum += alev;
                m = fmaxf(m, leaky(als[ed.x] + aldd + alev));
            }
        }
        #pragma unroll
        for (int off = 1; off < 64; off <<= 1) {
            m = fmaxf(m, __shfl_xor(m, off));
            asum += __shfl_xor(asum, off);
        }
        float self_al = leaky(alsn + aldd + asum * inv_deg);
        m = fmaxf(m, self_al);
        float den = 0.f;
        for (int base = s; base < e; base += 64) {
            int j = base + lane;
            if (j < e) {
                int4 ed = edata[j];
                int ai = (lsel == 0) ? ed.y : ((lsel == 1) ? ed.z : ed.w);
                den += __expf(leaky(als[ed.x] + aldd + __int_as_float(ai)) - m);
            }
        }
        #pragma unroll
        for (int off = 1; off < 64; off <<= 1) den += __shfl_xor(den, off);
        float es = __expf(self_al - m);
        den += es;
        float inv = 1.f / den;
        float wself = es * inv;
        ax = wself * hv.x;
        ay = wself * hv.y;
        for (int base = s; base < e; base += 64) {
            int cnt = min(e - base, 64);
            int sn = 0;
            float w = 0.f;
            if (lane < cnt) {
                int4 ed = edata[base + lane];
                sn = ed.x;
                int ai = (lsel == 0) ? ed.y : ((lsel == 1) ? ed.z : ed.w);
                w = __expf(leaky(als[sn] + aldd + __int_as_float(ai)) - m) * inv;
            }
            for (int t = 0; t < cnt; ++t) {
                int st = __shfl(sn, t);
                float wt = __shfl(w, t);
                float2 ht = ((const float2*)(h + (size_t)st * D))[lane];
                ax += wt * ht.x;
                ay += wt * ht.y;
            }
        }
    }

    float2 b2 = ((const float2*)bias)[lane];
    float ox = gelu_exact(ax + b2.x);
    float oy = gelu_exact(ay + b2.y);
    if (out_f32) {
        ((float2*)(out_f32 + (size_t)n * D))[lane] = make_float2(ox, oy);
    } else {
        unsigned short h0 = bf16_rne(ox);
        float h0f = __uint_as_float(((unsigned)h0) << 16);
        unsigned short l0 = bf16_rne(ox - h0f);
        unsigned short h1 = bf16_rne(oy);
        float h1f = __uint_as_float(((unsigned)h1) << 16);
        unsigned short l1 = bf16_rne(oy - h1f);
        out_hi[(size_t)n * 64 + lane] = (unsigned)h0 | ((unsigned)h1 << 16);
        out_lo[(size_t)n * 64 + lane] = (unsigned)l0 | ((unsigned)l1 << 16);
    }
}

// ---------------- launch ----------------

extern "C" void kernel_launch(void* const* d_in, const int* in_sizes, int n_in,
                              void* d_out, int out_size, void* d_ws, size_t ws_size,
                              hipStream_t stream) {
    (void)in_sizes; (void)n_in; (void)out_size; (void)ws_size;
    const float* x        = (const float*)d_in[0];
    const int*   eidx     = (const int*)d_in[1];   // [2, NE]: row0=src, row1=dst
    const float* ea       = (const float*)d_in[2];
    const float* Ws       = (const float*)d_in[3];
    const float* att_src  = (const float*)d_in[4];
    const float* att_dst  = (const float*)d_in[5];
    const float* W_edge   = (const float*)d_in[6];
    const float* att_edge = (const float*)d_in[7];
    const float* bias     = (const float*)d_in[8];
    float* out = (float*)d_out;

    char* ws = (char*)d_ws;
    size_t off = 0;
    auto alloc = [&](size_t bytes) {
        void* p = ws + off;
        off += (bytes + 255) & ~(size_t)255;
        return p;
    };
    float*          B0   = (float*)alloc((size_t)NN * D * 4);          // fp32 h after GEMM
    unsigned short* Hh   = (unsigned short*)alloc((size_t)NN * D * 2); // split-bf16 A (hi)
    unsigned short* Hl   = (unsigned short*)alloc((size_t)NN * D * 2); // split-bf16 A (lo)
    float*          als  = (float*)alloc((size_t)NN * 4);
    float*          ald  = (float*)alloc((size_t)NN * 4);
    int4*           edata= (int4*)alloc((size_t)NE * 16);              // (src, ale0, ale1, ale2)
    float*          wvec = (float*)alloc(3 * ED * 4);
    int*            deg  = (int*)alloc((size_t)NN * 4);
    int*            rp   = (int*)alloc((size_t)(NN + 4) * 4);
    int*            cursor = (int*)alloc((size_t)NN * 4);
    int*            bsum = (int*)alloc(256 * 4);
    int*            bscan= (int*)alloc(256 * 4);
    short*          Whp  = (short*)alloc((size_t)3 * D * D * 2);
    short*          Wlp  = (short*)alloc((size_t)3 * D * D * 2);

    const int* e_src = eidx;
    const int* e_dst = eidx + NE;

    // CSR build
    hipMemsetAsync(deg, 0, (size_t)NN * 4, stream);
    k_hist<<<NE / 256, 256, 0, stream>>>(e_dst, deg);
    k_scan1<<<NN / 256, 256, 0, stream>>>(deg, rp, bsum);
    k_scan2<<<1, 256, 0, stream>>>(bsum, bscan, rp);
    k_scan3<<<NN / 256, 256, 0, stream>>>(rp, bscan, cursor);

    // edge + weight precompute
    k_wvec<<<1, 128, 0, stream>>>(W_edge, att_edge, wvec);
    k_scatter_ale<<<NE / 256, 256, 0, stream>>>(e_src, e_dst, cursor, ea, wvec, edata);
    k_wpack<<<24, 256, 0, stream>>>(Ws, Whp, Wlp);
    k_splitx<<<(NN * D / 4) / 256, 256, 0, stream>>>(x, Hh, Hl);

    // layers
    for (int l = 0; l < 3; ++l) {
        k_gemm_mfma<<<NN / 128, 256, 0, stream>>>(Hh, Hl, Whp + (size_t)l * D * D, Wlp + (size_t)l * D * D,
                                                  att_src + (size_t)l * D, att_dst + (size_t)l * D,
                                                  B0, als, ald);
        bool last = (l == 2);
        k_aggr_fused<<<NN / 4, 256, 0, stream>>>(B0, als, ald, edata, rp, bias + (size_t)l * D, l,
                                                 last ? out : nullptr,
                                                 (unsigned*)Hh, (unsigned*)Hl);
    }
}

// Round 5
// 372.319 us; speedup vs baseline: 1.6767x; 1.1367x over previous
//
#include <hip/hip_runtime.h>
#include <math.h>

#define NN 65536        // nodes
#define NE 524288       // edges (without self loops)
#define D 128
#define ED 32
#define NEG_SLOPE 0.2f

typedef short bf16x8 __attribute__((ext_vector_type(8)));
typedef float f32x4 __attribute__((ext_vector_type(4)));
typedef unsigned short ushort_t;

__device__ __forceinline__ float leaky(float x) { return x > 0.f ? x : NEG_SLOPE * x; }
__device__ __forceinline__ float gelu_exact(float x) {
    return 0.5f * x * (1.f + erff(x * 0.70710678118654752440f));
}
__device__ __forceinline__ unsigned short bf16_rne(float x) {
    unsigned u = __float_as_uint(x);
    return (unsigned short)((u + 0x7FFFu + ((u >> 16) & 1u)) >> 16);
}
__device__ __forceinline__ void unpack8(int4 r, float* f) {
    unsigned u0 = (unsigned)r.x, u1 = (unsigned)r.y, u2 = (unsigned)r.z, u3 = (unsigned)r.w;
    f[0] = __uint_as_float(u0 << 16); f[1] = __uint_as_float(u0 & 0xFFFF0000u);
    f[2] = __uint_as_float(u1 << 16); f[3] = __uint_as_float(u1 & 0xFFFF0000u);
    f[4] = __uint_as_float(u2 << 16); f[5] = __uint_as_float(u2 & 0xFFFF0000u);
    f[6] = __uint_as_float(u3 << 16); f[7] = __uint_as_float(u3 & 0xFFFF0000u);
}

// ---------------- CSR build ----------------

__global__ void k_hist(const int* __restrict__ dst, int* __restrict__ deg) {
    int e = blockIdx.x * 256 + threadIdx.x;
    atomicAdd(&deg[dst[e]], 1);
}

__global__ void k_scan1(const int* __restrict__ deg, int* __restrict__ rp, int* __restrict__ bsum) {
    __shared__ int s[256];
    int t = threadIdx.x;
    int i = blockIdx.x * 256 + t;
    int v = deg[i];
    s[t] = v;
    __syncthreads();
    #pragma unroll
    for (int off = 1; off < 256; off <<= 1) {
        int x = (t >= off) ? s[t - off] : 0;
        __syncthreads();
        s[t] += x;
        __syncthreads();
    }
    rp[i] = s[t] - v;
    if (t == 255) bsum[blockIdx.x] = s[t];
}

__global__ void k_scan2(const int* __restrict__ bsum, int* __restrict__ bscan, int* __restrict__ rp) {
    __shared__ int s[256];
    int t = threadIdx.x;
    int v = bsum[t];
    s[t] = v;
    __syncthreads();
    #pragma unroll
    for (int off = 1; off < 256; off <<= 1) {
        int x = (t >= off) ? s[t - off] : 0;
        __syncthreads();
        s[t] += x;
        __syncthreads();
    }
    bscan[t] = s[t] - v;
    if (t == 255) rp[NN] = s[t];
}

__global__ void k_scan3(int* __restrict__ rp, const int* __restrict__ bscan, int* __restrict__ cursor) {
    int i = blockIdx.x * 256 + threadIdx.x;
    int v = rp[i] + bscan[blockIdx.x];
    rp[i] = v;
    cursor[i] = v;
}

// ---------------- edge precompute ----------------

__global__ void k_wvec(const float* __restrict__ We, const float* __restrict__ ae, float* __restrict__ wvec) {
    int t = threadIdx.x;
    if (t < 3 * ED) {
        int l = t / ED, k = t % ED;
        const float* w = We + (long)(l * ED + k) * D;
        const float* a = ae + (long)l * D;
        float s = 0.f;
        #pragma unroll
        for (int i = 0; i < D; ++i) s += w[i] * a[i];
        wvec[t] = s;
    }
}

// Fused scatter + ale: one packed record per CSR slot: (src, ale_l0, ale_l1, ale_l2)
__global__ void k_scatter_ale(const int* __restrict__ srcArr, const int* __restrict__ dstArr,
                              int* __restrict__ cursor, const float* __restrict__ ea,
                              const float* __restrict__ wvec, int4* __restrict__ edata) {
    int e = blockIdx.x * 256 + threadIdx.x;
    int d = dstArr[e];
    int p = atomicAdd(&cursor[d], 1);
    const float4* row = (const float4*)(ea + (long)e * ED);
    const float4* w0 = (const float4*)(wvec);
    const float4* w1 = (const float4*)(wvec + ED);
    const float4* w2 = (const float4*)(wvec + 2 * ED);
    float s0 = 0.f, s1 = 0.f, s2 = 0.f;
    #pragma unroll
    for (int i = 0; i < ED / 4; ++i) {
        float4 v = row[i];
        float4 a = w0[i], b = w1[i], c = w2[i];
        s0 += v.x * a.x + v.y * a.y + v.z * a.z + v.w * a.w;
        s1 += v.x * b.x + v.y * b.y + v.z * b.z + v.w * b.w;
        s2 += v.x * c.x + v.y * c.y + v.z * c.z + v.w * c.w;
    }
    edata[p] = make_int4(srcArr[e], __float_as_int(s0), __float_as_int(s1), __float_as_int(s2));
}

// Pack W (128x128 fp32) into MFMA B-fragment order, split bf16 hi/lo.
__global__ void k_wpack(const float* __restrict__ Ws, short* __restrict__ Whp, short* __restrict__ Wlp) {
    int t = blockIdx.x * 256 + threadIdx.x;
    if (t >= 3 * 4 * 4 * 128) return;
    int n = t & 127;
    int q = (t >> 7) & 3;
    int ks = (t >> 9) & 3;
    int l = t >> 11;
    const float* w = Ws + (size_t)l * D * D;
    size_t obase = (size_t)l * D * D + ((size_t)((ks * 4 + q) * 128) + n) * 8;
    #pragma unroll
    for (int j = 0; j < 8; ++j) {
        float x = w[(size_t)(ks * 32 + q * 8 + j) * D + n];
        unsigned short hb = bf16_rne(x);
        float hf = __uint_as_float(((unsigned)hb) << 16);
        Whp[obase + j] = (short)hb;
        Wlp[obase + j] = (short)bf16_rne(x - hf);
    }
}

// Split fp32 x into bf16 hi/lo (row-major), for layer-0 GEMM A.
__global__ void k_splitx(const float* __restrict__ x, ushort_t* __restrict__ Hh,
                         ushort_t* __restrict__ Hl) {
    int i = blockIdx.x * 256 + threadIdx.x;   // per float4
    float4 v = ((const float4*)x)[i];
    float xs[4] = {v.x, v.y, v.z, v.w};
    ushort4 h, l;
    ushort_t* hp = (ushort_t*)&h;
    ushort_t* lp = (ushort_t*)&l;
    #pragma unroll
    for (int j = 0; j < 4; ++j) {
        unsigned short hb = bf16_rne(xs[j]);
        float hf = __uint_as_float(((unsigned)hb) << 16);
        hp[j] = hb;
        lp[j] = bf16_rne(xs[j] - hf);
    }
    ((ushort4*)Hh)[i] = h;
    ((ushort4*)Hl)[i] = l;
}

// ---------------- per-layer kernels ----------------

// C = A @ W via split-bf16 MFMA; A pre-split bf16 hi/lo; B staged in LDS in two
// 32KB halves. One wave = 32 rows x 128 cols; block = 4 waves = 128 rows.
// Output h written as bf16 (gather consumption); als/ald written fp32 from acc.
__global__ __launch_bounds__(256) void k_gemm_mfma(const ushort_t* __restrict__ Ah,
        const ushort_t* __restrict__ Al,
        const short* __restrict__ Whp, const short* __restrict__ Wlp,
        const float* __restrict__ a_s, const float* __restrict__ a_d,
        ushort_t* __restrict__ Hb, float* __restrict__ als, float* __restrict__ ald) {
    __shared__ int4 BsH[1024];   // 16KB: hi half (8 slices x 128 cols x 8 bf16)
    __shared__ int4 BsL[1024];   // 16KB: lo half
    int t = threadIdx.x;
    int wave = t >> 6, lane = t & 63;
    int l16 = lane & 15, q = lane >> 4;
    int rows_base = blockIdx.x * 128 + wave * 32;

    const int4* wh4 = (const int4*)Whp;
    const int4* wl4 = (const int4*)Wlp;
    const short* bsh = (const short*)BsH;
    const short* bsl = (const short*)BsL;

    f32x4 acc[2][8] = {};
    #pragma unroll
    for (int h2 = 0; h2 < 2; ++h2) {
        if (h2) __syncthreads();
        #pragma unroll
        for (int i = 0; i < 4; ++i) {
            BsH[t + 256 * i] = wh4[h2 * 1024 + t + 256 * i];
            BsL[t + 256 * i] = wl4[h2 * 1024 + t + 256 * i];
        }
        __syncthreads();
        #pragma unroll
        for (int kk = 0; kk < 2; ++kk) {
            int ks = h2 * 2 + kk;
            bf16x8 ah[2], alo[2];
            #pragma unroll
            for (int mt = 0; mt < 2; ++mt) {
                size_t abase = (size_t)(rows_base + mt * 16 + l16) * D + ks * 32 + q * 8;
                ah[mt]  = *(const bf16x8*)(Ah + abase);
                alo[mt] = *(const bf16x8*)(Al + abase);
            }
            #pragma unroll
            for (int nt = 0; nt < 8; ++nt) {
                int idx = (((kk * 4 + q) * 128) + nt * 16 + l16) * 8;
                bf16x8 bh = *(const bf16x8*)(bsh + idx);
                bf16x8 bl = *(const bf16x8*)(bsl + idx);
                #pragma unroll
                for (int mt = 0; mt < 2; ++mt) {
                    acc[mt][nt] = __builtin_amdgcn_mfma_f32_16x16x32_bf16(ah[mt], bh, acc[mt][nt], 0, 0, 0);
                    acc[mt][nt] = __builtin_amdgcn_mfma_f32_16x16x32_bf16(ah[mt], bl, acc[mt][nt], 0, 0, 0);
                    acc[mt][nt] = __builtin_amdgcn_mfma_f32_16x16x32_bf16(alo[mt], bh, acc[mt][nt], 0, 0, 0);
                }
            }
        }
    }

    float as_r[8], ad_r[8];
    #pragma unroll
    for (int nt = 0; nt < 8; ++nt) {
        int col = nt * 16 + l16;
        as_r[nt] = a_s[col];
        ad_r[nt] = a_d[col];
    }
    #pragma unroll
    for (int mt = 0; mt < 2; ++mt) {
        #pragma unroll
        for (int r = 0; r < 4; ++r) {
            int row = rows_base + mt * 16 + q * 4 + r;
            float ps = 0.f, pd = 0.f;
            #pragma unroll
            for (int nt = 0; nt < 8; ++nt) {
                float v = acc[mt][nt][r];
                ps += v * as_r[nt];
                pd += v * ad_r[nt];
                Hb[(size_t)row * D + nt * 16 + l16] = bf16_rne(v);
            }
            #pragma unroll
            for (int off = 8; off >= 1; off >>= 1) {
                ps += __shfl_xor(ps, off);
                pd += __shfl_xor(pd, off);
            }
            if (l16 == 0) {
                als[row] = ps;
                ald[row] = pd;
            }
        }
    }
}

// Fused softmax + weighted gather. 16 lanes (quarter-wave) per dst node; each
// lane owns 8 cols (one dwordx4 of bf16 per gathered row). Fast path deg<=16.
__global__ __launch_bounds__(256) void k_aggr_fused(const ushort_t* __restrict__ hb,
        const float* __restrict__ als, const float* __restrict__ ald,
        const int4* __restrict__ edata, const int* __restrict__ rp,
        const float* __restrict__ bias, int lsel, float* __restrict__ out_f32,
        ushort_t* __restrict__ out_hi, ushort_t* __restrict__ out_lo) {
    int t = threadIdx.x;
    int lane = t & 63;
    int l16 = lane & 15;
    int qb = lane & 48;                 // quarter base within wave
    int n = blockIdx.x * 16 + (t >> 4); // one node per 16 threads
    int s = rp[n], e = rp[n + 1];
    int deg = e - s;
    float aldd = ald[n];
    float alsn = als[n];
    float inv_deg = (deg > 0) ? 1.f / (float)deg : 0.f;

    int4 hvp = *(const int4*)(hb + (size_t)n * D + l16 * 8);
    float acc8[8];

    if (deg <= 16) {
        int sn0 = 0;
        float al0 = -1e30f, alev0 = 0.f;
        if (l16 < deg) {
            int4 ed = edata[s + l16];
            sn0 = ed.x;
            alev0 = __int_as_float((lsel == 0) ? ed.y : ((lsel == 1) ? ed.z : ed.w));
            al0 = leaky(als[sn0] + aldd + alev0);
        }
        float mm = al0, asum = alev0;
        #pragma unroll
        for (int off = 1; off < 16; off <<= 1) {
            mm = fmaxf(mm, __shfl_xor(mm, off));
            asum += __shfl_xor(asum, off);
        }
        float self_al = leaky(alsn + aldd + asum * inv_deg);
        mm = fmaxf(mm, self_al);
        float p0 = (l16 < deg) ? __expf(al0 - mm) : 0.f;
        float den = p0;
        #pragma unroll
        for (int off = 1; off < 16; off <<= 1) den += __shfl_xor(den, off);
        float es = __expf(self_al - mm);
        den += es;
        float inv = 1.f / den;
        float w0 = p0 * inv;
        float wself = es * inv;

        float fv[8];
        unpack8(hvp, fv);
        #pragma unroll
        for (int j = 0; j < 8; ++j) acc8[j] = wself * fv[j];

        int tt = 0;
        for (; tt + 4 <= deg; tt += 4) {
            int   sA = __shfl(sn0, qb + tt),     sB = __shfl(sn0, qb + tt + 1);
            int   sC = __shfl(sn0, qb + tt + 2), sD = __shfl(sn0, qb + tt + 3);
            float wA = __shfl(w0, qb + tt),      wB = __shfl(w0, qb + tt + 1);
            float wC = __shfl(w0, qb + tt + 2),  wD = __shfl(w0, qb + tt + 3);
            int4 rA = *(const int4*)(hb + (size_t)sA * D + l16 * 8);
            int4 rB = *(const int4*)(hb + (size_t)sB * D + l16 * 8);
            int4 rC = *(const int4*)(hb + (size_t)sC * D + l16 * 8);
            int4 rD = *(const int4*)(hb + (size_t)sD * D + l16 * 8);
            float fA[8], fB[8], fC[8], fD[8];
            unpack8(rA, fA); unpack8(rB, fB); unpack8(rC, fC); unpack8(rD, fD);
            #pragma unroll
            for (int j = 0; j < 8; ++j)
                acc8[j] += wA * fA[j] + wB * fB[j] + wC * fC[j] + wD * fD[j];
        }
        for (; tt < deg; ++tt) {
            int st = __shfl(sn0, qb + tt);
            float wt = __shfl(w0, qb + tt);
            int4 r = *(const int4*)(hb + (size_t)st * D + l16 * 8);
            float f[8];
            unpack8(r, f);
            #pragma unroll
            for (int j = 0; j < 8; ++j) acc8[j] += wt * f[j];
        }
    } else {
        // general path (rare): chunked 3-pass with recompute
        float mm = -1e30f, asum = 0.f;
        for (int base = s; base < e; base += 16) {
            int j = base + l16;
            if (j < e) {
                int4 ed = edata[j];
                float alev = __int_as_float((lsel == 0) ? ed.y : ((lsel == 1) ? ed.z : ed.w));
                asum += alev;
                mm = fmaxf(mm, leaky(als[ed.x] + aldd + alev));
            }
        }
        #pragma unroll
        for (int off = 1; off < 16; off <<= 1) {
            mm = fmaxf(mm, __shfl_xor(mm, off));
            asum += __shfl_xor(asum, off);
        }
        float self_al = leaky(alsn + aldd + asum * inv_deg);
        mm = fmaxf(mm, self_al);
        float den = 0.f;
        for (int base = s; base < e; base += 16) {
            int j = base + l16;
            if (j < e) {
                int4 ed = edata[j];
                float alev = __int_as_float((lsel == 0) ? ed.y : ((lsel == 1) ? ed.z : ed.w));
                den += __expf(leaky(als[ed.x] + aldd + alev) - mm);
            }
        }
        #pragma unroll
        for (int off = 1; off < 16; off <<= 1) den += __shfl_xor(den, off);
        float es = __expf(self_al - mm);
        den += es;
        float inv = 1.f / den;
        float wself = es * inv;
        float fv[8];
        unpack8(hvp, fv);
        #pragma unroll
        for (int j = 0; j < 8; ++j) acc8[j] = wself * fv[j];
        for (int base = s; base < e; base += 16) {
            int cnt = min(e - base, 16);
            int sn = 0;
            float w = 0.f;
            if (l16 < cnt) {
                int4 ed = edata[base + l16];
                sn = ed.x;
                float alev = __int_as_float((lsel == 0) ? ed.y : ((lsel == 1) ? ed.z : ed.w));
                w = __expf(leaky(als[sn] + aldd + alev) - mm) * inv;
            }
            for (int tt = 0; tt < cnt; ++tt) {
                int st = __shfl(sn, qb + tt);
                float wt = __shfl(w, qb + tt);
                int4 r = *(const int4*)(hb + (size_t)st * D + l16 * 8);
                float f[8];
                unpack8(r, f);
                #pragma unroll
                for (int j = 0; j < 8; ++j) acc8[j] += wt * f[j];
            }
        }
    }

    const float4* b4 = (const float4*)(bias + l16 * 8);
    float4 b0 = b4[0], b1 = b4[1];
    float bb[8] = {b0.x, b0.y, b0.z, b0.w, b1.x, b1.y, b1.z, b1.w};
    float o[8];
    #pragma unroll
    for (int j = 0; j < 8; ++j) o[j] = gelu_exact(acc8[j] + bb[j]);

    if (out_f32) {
        float4* o4 = (float4*)(out_f32 + (size_t)n * D + l16 * 8);
        o4[0] = make_float4(o[0], o[1], o[2], o[3]);
        o4[1] = make_float4(o[4], o[5], o[6], o[7]);
    } else {
        ushort4 hi0, hi1, lo0, lo1;
        ushort_t* h0p = (ushort_t*)&hi0; ushort_t* h1p = (ushort_t*)&hi1;
        ushort_t* l0p = (ushort_t*)&lo0; ushort_t* l1p = (ushort_t*)&lo1;
        #pragma unroll
        for (int j = 0; j < 8; ++j) {
            unsigned short hb16 = bf16_rne(o[j]);
            float hf = __uint_as_float(((unsigned)hb16) << 16);
            unsigned short lb16 = bf16_rne(o[j] - hf);
            if (j < 4) { h0p[j] = hb16; l0p[j] = lb16; }
            else       { h1p[j - 4] = hb16; l1p[j - 4] = lb16; }
        }
        ushort4* oh = (ushort4*)(out_hi + (size_t)n * D + l16 * 8);
        ushort4* ol = (ushort4*)(out_lo + (size_t)n * D + l16 * 8);
        oh[0] = hi0; oh[1] = hi1;
        ol[0] = lo0; ol[1] = lo1;
    }
}

// ---------------- launch ----------------

extern "C" void kernel_launch(void* const* d_in, const int* in_sizes, int n_in,
                              void* d_out, int out_size, void* d_ws, size_t ws_size,
                              hipStream_t stream) {
    (void)in_sizes; (void)n_in; (void)out_size; (void)ws_size;
    const float* x        = (const float*)d_in[0];
    const int*   eidx     = (const int*)d_in[1];   // [2, NE]: row0=src, row1=dst
    const float* ea       = (const float*)d_in[2];
    const float* Ws       = (const float*)d_in[3];
    const float* att_src  = (const float*)d_in[4];
    const float* att_dst  = (const float*)d_in[5];
    const float* W_edge   = (const float*)d_in[6];
    const float* att_edge = (const float*)d_in[7];
    const float* bias     = (const float*)d_in[8];
    float* out = (float*)d_out;

    char* ws = (char*)d_ws;
    size_t off = 0;
    auto alloc = [&](size_t bytes) {
        void* p = ws + off;
        off += (bytes + 255) & ~(size_t)255;
        return p;
    };
    ushort_t* Hb   = (ushort_t*)alloc((size_t)NN * D * 2);  // bf16 h after GEMM (gather input)
    ushort_t* Hh   = (ushort_t*)alloc((size_t)NN * D * 2);  // split-bf16 A (hi)
    ushort_t* Hl   = (ushort_t*)alloc((size_t)NN * D * 2);  // split-bf16 A (lo)
    float*    als  = (float*)alloc((size_t)NN * 4);
    float*    ald  = (float*)alloc((size_t)NN * 4);
    int4*     edata= (int4*)alloc((size_t)NE * 16);         // (src, ale0, ale1, ale2)
    float*    wvec = (float*)alloc(3 * ED * 4);
    int*      deg  = (int*)alloc((size_t)NN * 4);
    int*      rp   = (int*)alloc((size_t)(NN + 4) * 4);
    int*      cursor = (int*)alloc((size_t)NN * 4);
    int*      bsum = (int*)alloc(256 * 4);
    int*      bscan= (int*)alloc(256 * 4);
    short*    Whp  = (short*)alloc((size_t)3 * D * D * 2);
    short*    Wlp  = (short*)alloc((size_t)3 * D * D * 2);

    const int* e_src = eidx;
    const int* e_dst = eidx + NE;

    // CSR build
    hipMemsetAsync(deg, 0, (size_t)NN * 4, stream);
    k_hist<<<NE / 256, 256, 0, stream>>>(e_dst, deg);
    k_scan1<<<NN / 256, 256, 0, stream>>>(deg, rp, bsum);
    k_scan2<<<1, 256, 0, stream>>>(bsum, bscan, rp);
    k_scan3<<<NN / 256, 256, 0, stream>>>(rp, bscan, cursor);

    // edge + weight precompute
    k_wvec<<<1, 128, 0, stream>>>(W_edge, att_edge, wvec);
    k_scatter_ale<<<NE / 256, 256, 0, stream>>>(e_src, e_dst, cursor, ea, wvec, edata);
    k_wpack<<<24, 256, 0, stream>>>(Ws, Whp, Wlp);
    k_splitx<<<(NN * D / 4) / 256, 256, 0, stream>>>(x, Hh, Hl);

    // layers
    for (int l = 0; l < 3; ++l) {
        k_gemm_mfma<<<NN / 128, 256, 0, stream>>>(Hh, Hl, Whp + (size_t)l * D * D, Wlp + (size_t)l * D * D,
                                                  att_src + (size_t)l * D, att_dst + (size_t)l * D,
                                                  Hb, als, ald);
        bool last = (l == 2);
        k_aggr_fused<<<NN / 16, 256, 0, stream>>>(Hb, als, ald, edata, rp, bias + (size_t)l * D, l,
                                                  last ? out : nullptr, Hh, Hl);
    }
}

// Round 6
// 366.953 us; speedup vs baseline: 1.7012x; 1.0146x over previous
//
#include <hip/hip_runtime.h>
#include <math.h>

#define NN 65536        // nodes
#define NE 524288       // edges (without self loops)
#define D 128
#define ED 32
#define NEG_SLOPE 0.2f

typedef short bf16x8 __attribute__((ext_vector_type(8)));
typedef float f32x4 __attribute__((ext_vector_type(4)));
typedef unsigned short ushort_t;

__device__ __forceinline__ float leaky(float x) { return x > 0.f ? x : NEG_SLOPE * x; }
__device__ __forceinline__ float gelu_exact(float x) {
    return 0.5f * x * (1.f + erff(x * 0.70710678118654752440f));
}
__device__ __forceinline__ unsigned short bf16_rne(float x) {
    unsigned u = __float_as_uint(x);
    return (unsigned short)((u + 0x7FFFu + ((u >> 16) & 1u)) >> 16);
}
__device__ __forceinline__ void unpack8(int4 r, float* f) {
    unsigned u0 = (unsigned)r.x, u1 = (unsigned)r.y, u2 = (unsigned)r.z, u3 = (unsigned)r.w;
    f[0] = __uint_as_float(u0 << 16); f[1] = __uint_as_float(u0 & 0xFFFF0000u);
    f[2] = __uint_as_float(u1 << 16); f[3] = __uint_as_float(u1 & 0xFFFF0000u);
    f[4] = __uint_as_float(u2 << 16); f[5] = __uint_as_float(u2 & 0xFFFF0000u);
    f[6] = __uint_as_float(u3 << 16); f[7] = __uint_as_float(u3 & 0xFFFF0000u);
}

// ---------------- edge precompute + CSR build ----------------

__global__ void k_wvec(const float* __restrict__ We, const float* __restrict__ ae, float* __restrict__ wvec) {
    int t = threadIdx.x;
    if (t < 3 * ED) {
        int l = t / ED, k = t % ED;
        const float* w = We + (long)(l * ED + k) * D;
        const float* a = ae + (long)l * D;
        float s = 0.f;
        #pragma unroll
        for (int i = 0; i < D; ++i) s += w[i] * a[i];
        wvec[t] = s;
    }
}

// Edge-order ale (coalesced) + degree histogram fused (atomic latency hidden
// under the BW-bound ea read).
__global__ void k_ale_hist(const float* __restrict__ ea, const float* __restrict__ wvec,
                           const int* __restrict__ dstArr, int* __restrict__ deg,
                           float* __restrict__ ale0, float* __restrict__ ale1,
                           float* __restrict__ ale2) {
    int e = blockIdx.x * 256 + threadIdx.x;
    atomicAdd(&deg[dstArr[e]], 1);
    const float4* row = (const float4*)(ea + (long)e * ED);
    const float4* w0 = (const float4*)(wvec);
    const float4* w1 = (const float4*)(wvec + ED);
    const float4* w2 = (const float4*)(wvec + 2 * ED);
    float s0 = 0.f, s1 = 0.f, s2 = 0.f;
    #pragma unroll
    for (int i = 0; i < ED / 4; ++i) {
        float4 v = row[i];
        float4 a = w0[i], b = w1[i], c = w2[i];
        s0 += v.x * a.x + v.y * a.y + v.z * a.z + v.w * a.w;
        s1 += v.x * b.x + v.y * b.y + v.z * b.z + v.w * b.w;
        s2 += v.x * c.x + v.y * c.y + v.z * c.z + v.w * c.w;
    }
    ale0[e] = s0;
    ale1[e] = s1;
    ale2[e] = s2;
}

__global__ void k_scan1(const int* __restrict__ deg, int* __restrict__ rp, int* __restrict__ bsum) {
    __shared__ int s[256];
    int t = threadIdx.x;
    int i = blockIdx.x * 256 + t;
    int v = deg[i];
    s[t] = v;
    __syncthreads();
    #pragma unroll
    for (int off = 1; off < 256; off <<= 1) {
        int x = (t >= off) ? s[t - off] : 0;
        __syncthreads();
        s[t] += x;
        __syncthreads();
    }
    rp[i] = s[t] - v;
    if (t == 255) bsum[blockIdx.x] = s[t];
}

__global__ void k_scan2(const int* __restrict__ bsum, int* __restrict__ bscan, int* __restrict__ rp) {
    __shared__ int s[256];
    int t = threadIdx.x;
    int v = bsum[t];
    s[t] = v;
    __syncthreads();
    #pragma unroll
    for (int off = 1; off < 256; off <<= 1) {
        int x = (t >= off) ? s[t - off] : 0;
        __syncthreads();
        s[t] += x;
        __syncthreads();
    }
    bscan[t] = s[t] - v;
    if (t == 255) rp[NN] = s[t];
}

__global__ void k_scan3(int* __restrict__ rp, const int* __restrict__ bscan, int* __restrict__ cursor) {
    int i = blockIdx.x * 256 + threadIdx.x;
    int v = rp[i] + bscan[blockIdx.x];
    rp[i] = v;
    cursor[i] = v;
}

// Scatter packed records; 4 edges per thread for 4x memory-level parallelism
// on the random atomic + random 16B store chain. All reads coalesced.
__global__ void k_scatter4(const int* __restrict__ srcArr, const int* __restrict__ dstArr,
                           int* __restrict__ cursor, const float* __restrict__ ale0,
                           const float* __restrict__ ale1, const float* __restrict__ ale2,
                           int4* __restrict__ edata) {
    int base = blockIdx.x * 1024 + threadIdx.x;
    int e[4], d[4], p[4];
    #pragma unroll
    for (int i = 0; i < 4; ++i) e[i] = base + 256 * i;
    #pragma unroll
    for (int i = 0; i < 4; ++i) d[i] = dstArr[e[i]];
    #pragma unroll
    for (int i = 0; i < 4; ++i) p[i] = atomicAdd(&cursor[d[i]], 1);
    #pragma unroll
    for (int i = 0; i < 4; ++i) {
        edata[p[i]] = make_int4(srcArr[e[i]], __float_as_int(ale0[e[i]]),
                                __float_as_int(ale1[e[i]]), __float_as_int(ale2[e[i]]));
    }
}

// Pack W (128x128 fp32) into MFMA B-fragment order, split bf16 hi/lo.
__global__ void k_wpack(const float* __restrict__ Ws, short* __restrict__ Whp, short* __restrict__ Wlp) {
    int t = blockIdx.x * 256 + threadIdx.x;
    if (t >= 3 * 4 * 4 * 128) return;
    int n = t & 127;
    int q = (t >> 7) & 3;
    int ks = (t >> 9) & 3;
    int l = t >> 11;
    const float* w = Ws + (size_t)l * D * D;
    size_t obase = (size_t)l * D * D + ((size_t)((ks * 4 + q) * 128) + n) * 8;
    #pragma unroll
    for (int j = 0; j < 8; ++j) {
        float x = w[(size_t)(ks * 32 + q * 8 + j) * D + n];
        unsigned short hb = bf16_rne(x);
        float hf = __uint_as_float(((unsigned)hb) << 16);
        Whp[obase + j] = (short)hb;
        Wlp[obase + j] = (short)bf16_rne(x - hf);
    }
}

// Split fp32 x into bf16 hi/lo (row-major), for layer-0 GEMM A.
__global__ void k_splitx(const float* __restrict__ x, ushort_t* __restrict__ Hh,
                         ushort_t* __restrict__ Hl) {
    int i = blockIdx.x * 256 + threadIdx.x;   // per float4
    float4 v = ((const float4*)x)[i];
    float xs[4] = {v.x, v.y, v.z, v.w};
    ushort4 h, l;
    ushort_t* hp = (ushort_t*)&h;
    ushort_t* lp = (ushort_t*)&l;
    #pragma unroll
    for (int j = 0; j < 4; ++j) {
        unsigned short hb = bf16_rne(xs[j]);
        float hf = __uint_as_float(((unsigned)hb) << 16);
        hp[j] = hb;
        lp[j] = bf16_rne(xs[j] - hf);
    }
    ((ushort4*)Hh)[i] = h;
    ((ushort4*)Hl)[i] = l;
}

// ---------------- per-layer kernels ----------------

// C = A @ W via split-bf16 MFMA; A pre-split bf16 hi/lo; B staged in LDS in two
// 32KB halves. One wave = 32 rows x 128 cols; block = 4 waves = 128 rows.
// Output h written as bf16 (gather consumption); als/ald written fp32 from acc.
__global__ __launch_bounds__(256) void k_gemm_mfma(const ushort_t* __restrict__ Ah,
        const ushort_t* __restrict__ Al,
        const short* __restrict__ Whp, const short* __restrict__ Wlp,
        const float* __restrict__ a_s, const float* __restrict__ a_d,
        ushort_t* __restrict__ Hb, float* __restrict__ als, float* __restrict__ ald) {
    __shared__ int4 BsH[1024];   // 16KB: hi half (8 slices x 128 cols x 8 bf16)
    __shared__ int4 BsL[1024];   // 16KB: lo half
    int t = threadIdx.x;
    int wave = t >> 6, lane = t & 63;
    int l16 = lane & 15, q = lane >> 4;
    int rows_base = blockIdx.x * 128 + wave * 32;

    const int4* wh4 = (const int4*)Whp;
    const int4* wl4 = (const int4*)Wlp;
    const short* bsh = (const short*)BsH;
    const short* bsl = (const short*)BsL;

    f32x4 acc[2][8] = {};
    #pragma unroll
    for (int h2 = 0; h2 < 2; ++h2) {
        if (h2) __syncthreads();
        #pragma unroll
        for (int i = 0; i < 4; ++i) {
            BsH[t + 256 * i] = wh4[h2 * 1024 + t + 256 * i];
            BsL[t + 256 * i] = wl4[h2 * 1024 + t + 256 * i];
        }
        __syncthreads();
        #pragma unroll
        for (int kk = 0; kk < 2; ++kk) {
            int ks = h2 * 2 + kk;
            bf16x8 ah[2], alo[2];
            #pragma unroll
            for (int mt = 0; mt < 2; ++mt) {
                size_t abase = (size_t)(rows_base + mt * 16 + l16) * D + ks * 32 + q * 8;
                ah[mt]  = *(const bf16x8*)(Ah + abase);
                alo[mt] = *(const bf16x8*)(Al + abase);
            }
            #pragma unroll
            for (int nt = 0; nt < 8; ++nt) {
                int idx = (((kk * 4 + q) * 128) + nt * 16 + l16) * 8;
                bf16x8 bh = *(const bf16x8*)(bsh + idx);
                bf16x8 bl = *(const bf16x8*)(bsl + idx);
                #pragma unroll
                for (int mt = 0; mt < 2; ++mt) {
                    acc[mt][nt] = __builtin_amdgcn_mfma_f32_16x16x32_bf16(ah[mt], bh, acc[mt][nt], 0, 0, 0);
                    acc[mt][nt] = __builtin_amdgcn_mfma_f32_16x16x32_bf16(ah[mt], bl, acc[mt][nt], 0, 0, 0);
                    acc[mt][nt] = __builtin_amdgcn_mfma_f32_16x16x32_bf16(alo[mt], bh, acc[mt][nt], 0, 0, 0);
                }
            }
        }
    }

    float as_r[8], ad_r[8];
    #pragma unroll
    for (int nt = 0; nt < 8; ++nt) {
        int col = nt * 16 + l16;
        as_r[nt] = a_s[col];
        ad_r[nt] = a_d[col];
    }
    #pragma unroll
    for (int mt = 0; mt < 2; ++mt) {
        #pragma unroll
        for (int r = 0; r < 4; ++r) {
            int row = rows_base + mt * 16 + q * 4 + r;
            float ps = 0.f, pd = 0.f;
            #pragma unroll
            for (int nt = 0; nt < 8; ++nt) {
                float v = acc[mt][nt][r];
                ps += v * as_r[nt];
                pd += v * ad_r[nt];
                Hb[(size_t)row * D + nt * 16 + l16] = bf16_rne(v);
            }
            #pragma unroll
            for (int off = 8; off >= 1; off >>= 1) {
                ps += __shfl_xor(ps, off);
                pd += __shfl_xor(pd, off);
            }
            if (l16 == 0) {
                als[row] = ps;
                ald[row] = pd;
            }
        }
    }
}

// Fused softmax + weighted gather. 16 lanes (quarter-wave) per dst node; each
// lane owns 8 cols (one dwordx4 of bf16 per gathered row). Fast path deg<=16.
__global__ __launch_bounds__(256) void k_aggr_fused(const ushort_t* __restrict__ hb,
        const float* __restrict__ als, const float* __restrict__ ald,
        const int4* __restrict__ edata, const int* __restrict__ rp,
        const float* __restrict__ bias, int lsel, float* __restrict__ out_f32,
        ushort_t* __restrict__ out_hi, ushort_t* __restrict__ out_lo) {
    int t = threadIdx.x;
    int lane = t & 63;
    int l16 = lane & 15;
    int qb = lane & 48;                 // quarter base within wave
    int n = blockIdx.x * 16 + (t >> 4); // one node per 16 threads
    int s = rp[n], e = rp[n + 1];
    int deg = e - s;
    float aldd = ald[n];
    float alsn = als[n];
    float inv_deg = (deg > 0) ? 1.f / (float)deg : 0.f;

    int4 hvp = *(const int4*)(hb + (size_t)n * D + l16 * 8);
    float acc8[8];

    if (deg <= 16) {
        int sn0 = 0;
        float al0 = -1e30f, alev0 = 0.f;
        if (l16 < deg) {
            int4 ed = edata[s + l16];
            sn0 = ed.x;
            alev0 = __int_as_float((lsel == 0) ? ed.y : ((lsel == 1) ? ed.z : ed.w));
            al0 = leaky(als[sn0] + aldd + alev0);
        }
        float mm = al0, asum = alev0;
        #pragma unroll
        for (int off = 1; off < 16; off <<= 1) {
            mm = fmaxf(mm, __shfl_xor(mm, off));
            asum += __shfl_xor(asum, off);
        }
        float self_al = leaky(alsn + aldd + asum * inv_deg);
        mm = fmaxf(mm, self_al);
        float p0 = (l16 < deg) ? __expf(al0 - mm) : 0.f;
        float den = p0;
        #pragma unroll
        for (int off = 1; off < 16; off <<= 1) den += __shfl_xor(den, off);
        float es = __expf(self_al - mm);
        den += es;
        float inv = 1.f / den;
        float w0 = p0 * inv;
        float wself = es * inv;

        float fv[8];
        unpack8(hvp, fv);
        #pragma unroll
        for (int j = 0; j < 8; ++j) acc8[j] = wself * fv[j];

        int tt = 0;
        for (; tt + 4 <= deg; tt += 4) {
            int   sA = __shfl(sn0, qb + tt),     sB = __shfl(sn0, qb + tt + 1);
            int   sC = __shfl(sn0, qb + tt + 2), sD = __shfl(sn0, qb + tt + 3);
            float wA = __shfl(w0, qb + tt),      wB = __shfl(w0, qb + tt + 1);
            float wC = __shfl(w0, qb + tt + 2),  wD = __shfl(w0, qb + tt + 3);
            int4 rA = *(const int4*)(hb + (size_t)sA * D + l16 * 8);
            int4 rB = *(const int4*)(hb + (size_t)sB * D + l16 * 8);
            int4 rC = *(const int4*)(hb + (size_t)sC * D + l16 * 8);
            int4 rD = *(const int4*)(hb + (size_t)sD * D + l16 * 8);
            float fA[8], fB[8], fC[8], fD[8];
            unpack8(rA, fA); unpack8(rB, fB); unpack8(rC, fC); unpack8(rD, fD);
            #pragma unroll
            for (int j = 0; j < 8; ++j)
                acc8[j] += wA * fA[j] + wB * fB[j] + wC * fC[j] + wD * fD[j];
        }
        for (; tt < deg; ++tt) {
            int st = __shfl(sn0, qb + tt);
            float wt = __shfl(w0, qb + tt);
            int4 r = *(const int4*)(hb + (size_t)st * D + l16 * 8);
            float f[8];
            unpack8(r, f);
            #pragma unroll
            for (int j = 0; j < 8; ++j) acc8[j] += wt * f[j];
        }
    } else {
        // general path (rare): chunked 3-pass with recompute
        float mm = -1e30f, asum = 0.f;
        for (int base = s; base < e; base += 16) {
            int j = base + l16;
            if (j < e) {
                int4 ed = edata[j];
                float alev = __int_as_float((lsel == 0) ? ed.y : ((lsel == 1) ? ed.z : ed.w));
                asum += alev;
                mm = fmaxf(mm, leaky(als[ed.x] + aldd + alev));
            }
        }
        #pragma unroll
        for (int off = 1; off < 16; off <<= 1) {
            mm = fmaxf(mm, __shfl_xor(mm, off));
            asum += __shfl_xor(asum, off);
        }
        float self_al = leaky(alsn + aldd + asum * inv_deg);
        mm = fmaxf(mm, self_al);
        float den = 0.f;
        for (int base = s; base < e; base += 16) {
            int j = base + l16;
            if (j < e) {
                int4 ed = edata[j];
                float alev = __int_as_float((lsel == 0) ? ed.y : ((lsel == 1) ? ed.z : ed.w));
                den += __expf(leaky(als[ed.x] + aldd + alev) - mm);
            }
        }
        #pragma unroll
        for (int off = 1; off < 16; off <<= 1) den += __shfl_xor(den, off);
        float es = __expf(self_al - mm);
        den += es;
        float inv = 1.f / den;
        float wself = es * inv;
        float fv[8];
        unpack8(hvp, fv);
        #pragma unroll
        for (int j = 0; j < 8; ++j) acc8[j] = wself * fv[j];
        for (int base = s; base < e; base += 16) {
            int cnt = min(e - base, 16);
            int sn = 0;
            float w = 0.f;
            if (l16 < cnt) {
                int4 ed = edata[base + l16];
                sn = ed.x;
                float alev = __int_as_float((lsel == 0) ? ed.y : ((lsel == 1) ? ed.z : ed.w));
                w = __expf(leaky(als[sn] + aldd + alev) - mm) * inv;
            }
            for (int tt = 0; tt < cnt; ++tt) {
                int st = __shfl(sn, qb + tt);
                float wt = __shfl(w, qb + tt);
                int4 r = *(const int4*)(hb + (size_t)st * D + l16 * 8);
                float f[8];
                unpack8(r, f);
                #pragma unroll
                for (int j = 0; j < 8; ++j) acc8[j] += wt * f[j];
            }
        }
    }

    const float4* b4 = (const float4*)(bias + l16 * 8);
    float4 b0 = b4[0], b1 = b4[1];
    float bb[8] = {b0.x, b0.y, b0.z, b0.w, b1.x, b1.y, b1.z, b1.w};
    float o[8];
    #pragma unroll
    for (int j = 0; j < 8; ++j) o[j] = gelu_exact(acc8[j] + bb[j]);

    if (out_f32) {
        float4* o4 = (float4*)(out_f32 + (size_t)n * D + l16 * 8);
        o4[0] = make_float4(o[0], o[1], o[2], o[3]);
        o4[1] = make_float4(o[4], o[5], o[6], o[7]);
    } else {
        ushort4 hi0, hi1, lo0, lo1;
        ushort_t* h0p = (ushort_t*)&hi0; ushort_t* h1p = (ushort_t*)&hi1;
        ushort_t* l0p = (ushort_t*)&lo0; ushort_t* l1p = (ushort_t*)&lo1;
        #pragma unroll
        for (int j = 0; j < 8; ++j) {
            unsigned short hb16 = bf16_rne(o[j]);
            float hf = __uint_as_float(((unsigned)hb16) << 16);
            unsigned short lb16 = bf16_rne(o[j] - hf);
            if (j < 4) { h0p[j] = hb16; l0p[j] = lb16; }
            else       { h1p[j - 4] = hb16; l1p[j - 4] = lb16; }
        }
        ushort4* oh = (ushort4*)(out_hi + (size_t)n * D + l16 * 8);
        ushort4* ol = (ushort4*)(out_lo + (size_t)n * D + l16 * 8);
        oh[0] = hi0; oh[1] = hi1;
        ol[0] = lo0; ol[1] = lo1;
    }
}

// ---------------- launch ----------------

extern "C" void kernel_launch(void* const* d_in, const int* in_sizes, int n_in,
                              void* d_out, int out_size, void* d_ws, size_t ws_size,
                              hipStream_t stream) {
    (void)in_sizes; (void)n_in; (void)out_size; (void)ws_size;
    const float* x        = (const float*)d_in[0];
    const int*   eidx     = (const int*)d_in[1];   // [2, NE]: row0=src, row1=dst
    const float* ea       = (const float*)d_in[2];
    const float* Ws       = (const float*)d_in[3];
    const float* att_src  = (const float*)d_in[4];
    const float* att_dst  = (const float*)d_in[5];
    const float* W_edge   = (const float*)d_in[6];
    const float* att_edge = (const float*)d_in[7];
    const float* bias     = (const float*)d_in[8];
    float* out = (float*)d_out;

    char* ws = (char*)d_ws;
    size_t off = 0;
    auto alloc = [&](size_t bytes) {
        void* p = ws + off;
        off += (bytes + 255) & ~(size_t)255;
        return p;
    };
    ushort_t* Hb   = (ushort_t*)alloc((size_t)NN * D * 2);  // bf16 h after GEMM (gather input)
    ushort_t* Hh   = (ushort_t*)alloc((size_t)NN * D * 2);  // split-bf16 A (hi)
    ushort_t* Hl   = (ushort_t*)alloc((size_t)NN * D * 2);  // split-bf16 A (lo)
    float*    als  = (float*)alloc((size_t)NN * 4);
    float*    ald  = (float*)alloc((size_t)NN * 4);
    int4*     edata= (int4*)alloc((size_t)NE * 16);         // (src, ale0, ale1, ale2)
    float*    ale0 = (float*)alloc((size_t)NE * 4);         // edge-order ale per layer
    float*    ale1 = (float*)alloc((size_t)NE * 4);
    float*    ale2 = (float*)alloc((size_t)NE * 4);
    float*    wvec = (float*)alloc(3 * ED * 4);
    int*      deg  = (int*)alloc((size_t)NN * 4);
    int*      rp   = (int*)alloc((size_t)(NN + 4) * 4);
    int*      cursor = (int*)alloc((size_t)NN * 4);
    int*      bsum = (int*)alloc(256 * 4);
    int*      bscan= (int*)alloc(256 * 4);
    short*    Whp  = (short*)alloc((size_t)3 * D * D * 2);
    short*    Wlp  = (short*)alloc((size_t)3 * D * D * 2);

    const int* e_src = eidx;
    const int* e_dst = eidx + NE;

    // CSR build + edge precompute
    hipMemsetAsync(deg, 0, (size_t)NN * 4, stream);
    k_wvec<<<1, 128, 0, stream>>>(W_edge, att_edge, wvec);
    k_ale_hist<<<NE / 256, 256, 0, stream>>>(ea, wvec, e_dst, deg, ale0, ale1, ale2);
    k_scan1<<<NN / 256, 256, 0, stream>>>(deg, rp, bsum);
    k_scan2<<<1, 256, 0, stream>>>(bsum, bscan, rp);
    k_scan3<<<NN / 256, 256, 0, stream>>>(rp, bscan, cursor);
    k_scatter4<<<NE / 1024, 256, 0, stream>>>(e_src, e_dst, cursor, ale0, ale1, ale2, edata);

    // weight precompute
    k_wpack<<<24, 256, 0, stream>>>(Ws, Whp, Wlp);
    k_splitx<<<(NN * D / 4) / 256, 256, 0, stream>>>(x, Hh, Hl);

    // layers
    for (int l = 0; l < 3; ++l) {
        k_gemm_mfma<<<NN / 128, 256, 0, stream>>>(Hh, Hl, Whp + (size_t)l * D * D, Wlp + (size_t)l * D * D,
                                                  att_src + (size_t)l * D, att_dst + (size_t)l * D,
                                                  Hb, als, ald);
        bool last = (l == 2);
        k_aggr_fused<<<NN / 16, 256, 0, stream>>>(Hb, als, ald, edata, rp, bias + (size_t)l * D, l,
                                                  last ? out : nullptr, Hh, Hl);
    }
}